// Round 5
// baseline (1215.945 us; speedup 1.0000x reference)
//
#include <hip/hip_runtime.h>
#include <hip/hip_bf16.h>
#include <stdint.h>
#include <stddef.h>

typedef __attribute__((ext_vector_type(8))) __bf16 bf16x8;
typedef __attribute__((ext_vector_type(4))) float f32x4;

#define MFMA16(a, b, c) __builtin_amdgcn_mfma_f32_16x16x32_bf16((a), (b), (c), 0, 0, 0)

static constexpr int Bc = 4, Nc = 4096, Dc = 1024, Hc = 16, HDc = 64;

__device__ __forceinline__ uint16_t f2bf(float f) {
  __bf16 h = (__bf16)f;
  return __builtin_bit_cast(uint16_t, h);
}

// async global->LDS, 16B per lane. LDS dest must be wave-uniform base + lane*16.
__device__ __forceinline__ void gload16(const void* g, void* l) {
  __builtin_amdgcn_global_load_lds(
      (__attribute__((address_space(1))) void*)(g),
      (__attribute__((address_space(3))) void*)(l), 16, 0, 0);
}

// ---------------------------------------------------------------------------
// f32 -> bf16 convert (vectorized, 8 elems/thread). n must be a multiple of 8.
// ---------------------------------------------------------------------------
__global__ __launch_bounds__(256) void cvt_f32_bf16(
    const float* __restrict__ src, uint16_t* __restrict__ dst, int n) {
  const int i = (blockIdx.x * 256 + threadIdx.x) * 8;
  if (i >= n) return;
  const float4 a = *(const float4*)(src + i);
  const float4 b = *(const float4*)(src + i + 4);
  union { uint16_t u[8]; uint4 v; } o;
  o.u[0] = f2bf(a.x); o.u[1] = f2bf(a.y); o.u[2] = f2bf(a.z); o.u[3] = f2bf(a.w);
  o.u[4] = f2bf(b.x); o.u[5] = f2bf(b.y); o.u[6] = f2bf(b.z); o.u[7] = f2bf(b.w);
  *(uint4*)(dst + i) = o.v;
}

// ---------------------------------------------------------------------------
// BT-GEMM: C[m, e] = sum_k A[m, k] * Bw[e, k].  128x128 tile, BK=64, 4 waves.
// EPI=0: QKV projection epilogue -> RoPE (f32 rot) -> Q/K [B,H,N,HD] bf16,
//        Q pre-scaled by 0.125*log2(e) (exp2-domain softmax),
//        V transposed [B,H,HD,N] bf16
// EPI=1: bias add (f32) -> Out [M, 1024] f32
// ---------------------------------------------------------------------------
template <int EPI>
__global__ __launch_bounds__(256, 2) void gemm_bt(
    const uint16_t* __restrict__ A, const uint16_t* __restrict__ Bw, int K,
    const float* __restrict__ rot, uint16_t* __restrict__ Qb,
    uint16_t* __restrict__ Kb, uint16_t* __restrict__ Vg,
    const float* __restrict__ bias, float* __restrict__ Out) {
  __shared__ __align__(16) uint16_t As[128 * 64];
  __shared__ __align__(16) uint16_t Bs[128 * 64];
  const int tid = threadIdx.x;
  const int lane = tid & 63, wave = tid >> 6;
  const int l15 = lane & 15, g = lane >> 4;
  const int wr = wave >> 1, wc = wave & 1;
  const int m0 = blockIdx.y * 128;
  const int n0 = blockIdx.x * 128;

  f32x4 acc[4][4];
  const f32x4 fz = {0.f, 0.f, 0.f, 0.f};
#pragma unroll
  for (int i = 0; i < 4; ++i)
#pragma unroll
    for (int j = 0; j < 4; ++j) acc[i][j] = fz;

  for (int kt = 0; kt < K; kt += 64) {
    __syncthreads();  // previous iter's LDS reads done before overwrite
#pragma unroll
    for (int i = 0; i < 4; ++i) {
      const int chunk = tid + i * 256;  // 0..1023 : 128 rows x 8 chunks(16B)
      const int r = chunk >> 3, c = chunk & 7;
      const int cs = c ^ (r & 7);  // pre-swizzled source (linear LDS dest)
      gload16(A + (size_t)(m0 + r) * K + kt + cs * 8, &As[chunk * 8]);
      gload16(Bw + (size_t)(n0 + r) * K + kt + cs * 8, &Bs[chunk * 8]);
    }
    __syncthreads();  // implies vmcnt(0): staged data visible

    bf16x8 af[4][2], bfr[4][2];
#pragma unroll
    for (int mi = 0; mi < 4; ++mi)
#pragma unroll
      for (int kk = 0; kk < 2; ++kk) {
        const int r = wr * 64 + mi * 16 + l15;
        const int ca = (kk * 4 + g) ^ (r & 7);
        af[mi][kk] = *(const bf16x8*)((const char*)As + r * 128 + ca * 16);
        const int r2 = wc * 64 + mi * 16 + l15;
        const int cb = (kk * 4 + g) ^ (r2 & 7);
        bfr[mi][kk] = *(const bf16x8*)((const char*)Bs + r2 * 128 + cb * 16);
      }
#pragma unroll
    for (int mi = 0; mi < 4; ++mi)
#pragma unroll
      for (int nj = 0; nj < 4; ++nj)
#pragma unroll
        for (int kk = 0; kk < 2; ++kk)
          acc[mi][nj] = MFMA16(af[mi][kk], bfr[nj][kk], acc[mi][nj]);
  }

  if (EPI == 0) {
    // C rows m -> (b, n); cols e -> (part, h, hd). RoPE pair is lane^1.
    const int b = m0 >> 12;  // 4096 rows per batch, 128 | 4096 -> uniform
#pragma unroll
    for (int nj = 0; nj < 4; ++nj) {
      const int e = n0 + wc * 64 + nj * 16 + l15;
      const int part = e >> 10;           // wave-uniform (16-col tile)
      const int d = e & 1023;
      const int h = d >> 6, hd = d & 63;
      // exp2-domain: fold 0.125*log2(e) into Q
      const float sc = (part == 0) ? 0.18033688011112042f : 1.0f;
#pragma unroll
      for (int mi = 0; mi < 4; ++mi) {
        if (part == 2) {
          // V transposed: [B, H, HD, N]; pack 4 consecutive n into 8B store
          const int nb = (m0 & 4095) + wr * 64 + mi * 16 + g * 4;
          uint2 pv;
          pv.x = (uint32_t)f2bf(acc[mi][nj][0]) |
                 ((uint32_t)f2bf(acc[mi][nj][1]) << 16);
          pv.y = (uint32_t)f2bf(acc[mi][nj][2]) |
                 ((uint32_t)f2bf(acc[mi][nj][3]) << 16);
          *(uint2*)(Vg + ((size_t)(b * Hc + h) * HDc + hd) * Nc + nb) = pv;
        } else {
          uint16_t* dst = (part == 0) ? Qb : Kb;
          const size_t base = ((size_t)(b * Hc + h) * Nc) * HDc + hd;
#pragma unroll
          for (int rg = 0; rg < 4; ++rg) {
            const int m = m0 + wr * 64 + mi * 16 + g * 4 + rg;
            const int n = m & (Nc - 1);
            const float val = acc[mi][nj][rg];
            const float partner = __shfl_xor(val, 1);
            const float x2 = (e & 1) ? partner : -partner;
            const float2 cs =
                *(const float2*)(rot + ((size_t)(b * Nc + n) * Dc + d) * 2);
            dst[base + (size_t)n * HDc] = f2bf((val * cs.x + x2 * cs.y) * sc);
          }
        }
      }
    }
  } else {
#pragma unroll
    for (int nj = 0; nj < 4; ++nj) {
      const int e = n0 + wc * 64 + nj * 16 + l15;
      const float bia = bias[e];
#pragma unroll
      for (int mi = 0; mi < 4; ++mi)
#pragma unroll
        for (int rg = 0; rg < 4; ++rg) {
          const int m = m0 + wr * 64 + mi * 16 + g * 4 + rg;
          Out[(size_t)m * Dc + e] = acc[mi][nj][rg] + bia;
        }
    }
  }
}

// ---------------------------------------------------------------------------
// Flash attention, swapped-QK + swapped-PV, exp2-domain softmax, static
// double-buffer (t+=2 unroll -> all LDS addresses compile-time), chunk-XOR
// swizzled P tile (conflict-free geometry), defer-rescale (T13), setprio (T5).
// ---------------------------------------------------------------------------
__global__ __launch_bounds__(256, 4) void attn_fa(
    const uint16_t* __restrict__ Qb, const uint16_t* __restrict__ Kb,
    const uint16_t* __restrict__ Vg, uint16_t* __restrict__ Ob) {
  __shared__ __align__(16) uint16_t Ks[2][64 * 64];  // [kv][d], chunk-swizzled
  __shared__ __align__(16) uint16_t Vt[2][64 * 64];  // [d][kv], chunk-swizzled
  __shared__ __align__(16) uint16_t Pl[4][16 * 64];  // per-wave P [q][kv], swz
  const int tid = threadIdx.x;
  const int lane = tid & 63, wave = tid >> 6;
  const int l15 = lane & 15, g = lane >> 4;
  const int swz = l15 & 7;
  const int bh = blockIdx.y;
  const int q0 = blockIdx.x * 128;
  const size_t bhN = (size_t)bh * Nc;
  const size_t bhHD = (size_t)bh * HDc;
  char* plw = (char*)&Pl[wave][0] + l15 * 128;  // this lane's q-row base

  // Q fragments register-resident for the whole block (B-operand layout)
  bf16x8 qf[2][2];
#pragma unroll
  for (int rf = 0; rf < 2; ++rf)
#pragma unroll
    for (int kk = 0; kk < 2; ++kk)
      qf[rf][kk] = *(const bf16x8*)(Qb + (bhN + q0 + wave * 32 + rf * 16 + l15) * HDc +
                                    kk * 32 + g * 8);

  const f32x4 fz = {0.f, 0.f, 0.f, 0.f};
  f32x4 O[2][4];
  float mrow[2] = {-1e30f, -1e30f}, lrow[2] = {0.f, 0.f};
#pragma unroll
  for (int rf = 0; rf < 2; ++rf)
#pragma unroll
    for (int df = 0; df < 4; ++df) O[rf][df] = fz;

  // stage K/V tile t into given LDS buffers (linear dest, pre-swz source)
  auto stage = [&](uint16_t* ksd, uint16_t* vtd, int t) {
    const int kv0 = t * 64;
#pragma unroll
    for (int i = 0; i < 2; ++i) {
      const int ch = tid + i * 256;  // 0..511 : 64 rows x 8 chunks(16B)
      const int r = ch >> 3, c = ch & 7;
      const int cs = c ^ (r & 7);
      gload16(Kb + (bhN + kv0 + r) * HDc + cs * 8, ksd + ch * 8);
      gload16(Vg + (bhHD + r) * Nc + kv0 + cs * 8, vtd + ch * 8);
    }
  };

  auto compute = [&](const uint16_t* ks, const uint16_t* vt) {
    // St[rf][cf]: lane(g,l15) reg r4 = S'[q=l15+rf*16][kv=cf*16+g*4+r4]
    f32x4 St[2][4];
#pragma unroll
    for (int rf = 0; rf < 2; ++rf)
#pragma unroll
      for (int cf = 0; cf < 4; ++cf) St[rf][cf] = fz;
    __builtin_amdgcn_s_setprio(1);
#pragma unroll
    for (int cf = 0; cf < 4; ++cf)
#pragma unroll
      for (int kk = 0; kk < 2; ++kk) {
        bf16x8 kf = *(const bf16x8*)(&ks[(cf * 16 + l15) * 64 + ((kk * 4 + g) ^ swz) * 8]);
        St[0][cf] = MFMA16(kf, qf[0][kk], St[0][cf]);
        St[1][cf] = MFMA16(kf, qf[1][kk], St[1][cf]);
      }
    __builtin_amdgcn_s_setprio(0);

    // V fragments (A-operand: row = d = df*16+l15)
    bf16x8 vb[4][2];
#pragma unroll
    for (int df = 0; df < 4; ++df) {
      vb[df][0] = *(const bf16x8*)(&vt[(df * 16 + l15) * 64 + (g ^ swz) * 8]);
      vb[df][1] = *(const bf16x8*)(&vt[(df * 16 + l15) * 64 + ((4 + g) ^ swz) * 8]);
    }

#pragma unroll
    for (int rf = 0; rf < 2; ++rf) {
      // tile max (tree; max3-fusable) then combine 4 g-groups
      f32x4 m01, m23;
#pragma unroll
      for (int j = 0; j < 4; ++j) {
        m01[j] = fmaxf(St[rf][0][j], St[rf][1][j]);
        m23[j] = fmaxf(St[rf][2][j], St[rf][3][j]);
      }
      float pm = fmaxf(fmaxf(fmaxf(m01[0], m01[1]), fmaxf(m01[2], m01[3])),
                       fmaxf(fmaxf(m23[0], m23[1]), fmaxf(m23[2], m23[3])));
      pm = fmaxf(pm, __shfl_xor(pm, 16));
      pm = fmaxf(pm, __shfl_xor(pm, 32));

      // defer-rescale (exp2 domain): only pay the O-pass when max grew >11.5
      if (__any(pm > mrow[rf] + 11.5f)) {
        const float mN = fmaxf(mrow[rf], pm);
        const float corr = exp2f(mrow[rf] - mN);
        mrow[rf] = mN;
        lrow[rf] *= corr;
#pragma unroll
        for (int df = 0; df < 4; ++df)
#pragma unroll
          for (int r4 = 0; r4 < 4; ++r4) O[rf][df][r4] *= corr;
      }
      const float mN = mrow[rf];

#pragma unroll
      for (int cf = 0; cf < 4; ++cf)
#pragma unroll
        for (int r4 = 0; r4 < 4; ++r4) St[rf][cf][r4] = exp2f(St[rf][cf][r4] - mN);
      f32x4 s01, s23;
#pragma unroll
      for (int j = 0; j < 4; ++j) {
        s01[j] = St[rf][0][j] + St[rf][1][j];
        s23[j] = St[rf][2][j] + St[rf][3][j];
      }
      float rs = ((s01[0] + s01[1]) + (s01[2] + s01[3])) +
                 ((s23[0] + s23[1]) + (s23[2] + s23[3]));
      rs += __shfl_xor(rs, 16);
      rs += __shfl_xor(rs, 32);
      lrow[rf] += rs;

      // P pack into chunk-XOR swizzled [q][kv] tile: elem (q,kv) at byte
      // q*128 + ((kv>>3)^(q&7))*16 + (kv&7)*2. Lane writes kv=cf*16+g*4+r4.
#pragma unroll
      for (int cf = 0; cf < 4; ++cf) {
        uint2 pv;
        pv.x = (uint32_t)f2bf(St[rf][cf][0]) | ((uint32_t)f2bf(St[rf][cf][1]) << 16);
        pv.y = (uint32_t)f2bf(St[rf][cf][2]) | ((uint32_t)f2bf(St[rf][cf][3]) << 16);
        *(uint2*)(plw + (((cf * 2 + (g >> 1)) ^ swz) * 16) + (g & 1) * 8) = pv;
      }

      // PV with swapped args: Ot[col=q=l15][row=d] = mfma(V-frag, P-frag)
      bf16x8 pa0 = *(const bf16x8*)(plw + ((g ^ swz) * 16));
      bf16x8 pa1 = *(const bf16x8*)(plw + (((4 + g) ^ swz) * 16));
      __builtin_amdgcn_s_setprio(1);
#pragma unroll
      for (int df = 0; df < 4; ++df) {
        O[rf][df] = MFMA16(vb[df][0], pa0, O[rf][df]);
        O[rf][df] = MFMA16(vb[df][1], pa1, O[rf][df]);
      }
      __builtin_amdgcn_s_setprio(0);
    }
  };

  stage(Ks[0], Vt[0], 0);
  for (int t = 0; t < Nc / 64; t += 2) {
    __syncthreads();                    // tile t (buf0) visible
    stage(Ks[1], Vt[1], t + 1);         // flies under compute(buf0)
    compute(Ks[0], Vt[0]);
    __syncthreads();                    // tile t+1 (buf1) visible; buf0 free
    if (t + 2 < Nc / 64) stage(Ks[0], Vt[0], t + 2);
    compute(Ks[1], Vt[1]);
  }

  // epilogue: per-lane normalize (q = l15), packed 8B stores
  const int b = bh >> 4, h = bh & 15;
#pragma unroll
  for (int rf = 0; rf < 2; ++rf) {
    const float inv = 1.f / lrow[rf];
    const int n = q0 + wave * 32 + rf * 16 + l15;
    uint16_t* orow = Ob + ((size_t)b * Nc + n) * Dc + h * HDc;
#pragma unroll
    for (int df = 0; df < 4; ++df) {
      uint2 pv;
      pv.x = (uint32_t)f2bf(O[rf][df][0] * inv) |
             ((uint32_t)f2bf(O[rf][df][1] * inv) << 16);
      pv.y = (uint32_t)f2bf(O[rf][df][2] * inv) |
             ((uint32_t)f2bf(O[rf][df][3] * inv) << 16);
      *(uint2*)(orow + df * 16 + g * 4) = pv;
    }
  }
}

extern "C" void kernel_launch(void* const* d_in, const int* in_sizes, int n_in,
                              void* d_out, int out_size, void* d_ws, size_t ws_size,
                              hipStream_t stream) {
  const float* x = (const float*)d_in[0];      // [B,N,D] f32
  const float* rot = (const float*)d_in[1];    // [B,N,D,2] f32
  const float* Wqkv = (const float*)d_in[2];   // [3D,D] f32
  const float* Wout = (const float*)d_in[3];   // [D,D] f32
  const float* bout = (const float*)d_in[4];   // [D] f32
  float* out = (float*)d_out;                  // [B,N,D] f32

  uint16_t* ws = (uint16_t*)d_ws;
  const size_t XSZ = (size_t)Bc * Nc * Dc;        // 16,777,216 elems
  const size_t W1SZ = (size_t)3 * Dc * Dc;        //  3,145,728
  const size_t W2SZ = (size_t)Dc * Dc;            //  1,048,576
  uint16_t* xb = ws;               // bf16 x; ALIASED with At (safe: xb's last
  uint16_t* At = ws;               // read is gemm1; At first written by attn)
  uint16_t* Qb = ws + XSZ;
  uint16_t* Kb = ws + 2 * XSZ;
  uint16_t* Vg = ws + 3 * XSZ;     // transposed [B,H,HD,N]
  uint16_t* Wqb = ws + 4 * XSZ;
  uint16_t* Wob = ws + 4 * XSZ + W1SZ;
  // total: 4*XSZ + W1SZ + W2SZ = 71,303,168 elems = 142.6 MB

  dim3 blk(256);
  cvt_f32_bf16<<<dim3((XSZ / 8 + 255) / 256), blk, 0, stream>>>(x, xb, (int)XSZ);
  cvt_f32_bf16<<<dim3((W1SZ / 8 + 255) / 256), blk, 0, stream>>>(Wqkv, Wqb, (int)W1SZ);
  cvt_f32_bf16<<<dim3((W2SZ / 8 + 255) / 256), blk, 0, stream>>>(Wout, Wob, (int)W2SZ);

  gemm_bt<0><<<dim3((3 * Dc) / 128, (Bc * Nc) / 128), blk, 0, stream>>>(
      xb, Wqb, Dc, rot, Qb, Kb, Vg, nullptr, nullptr);
  attn_fa<<<dim3(Nc / 128, Bc * Hc), blk, 0, stream>>>(Qb, Kb, Vg, At);
  gemm_bt<1><<<dim3(Dc / 128, (Bc * Nc) / 128), blk, 0, stream>>>(
      At, Wob, Dc, nullptr, nullptr, nullptr, nullptr, bout, out);
}

// Round 6
// 796.681 us; speedup vs baseline: 1.5263x; 1.5263x over previous
//
#include <hip/hip_runtime.h>
#include <hip/hip_bf16.h>
#include <stdint.h>
#include <stddef.h>

typedef __attribute__((ext_vector_type(8))) __bf16 bf16x8;
typedef __attribute__((ext_vector_type(4))) float f32x4;

#define MFMA16(a, b, c) __builtin_amdgcn_mfma_f32_16x16x32_bf16((a), (b), (c), 0, 0, 0)

static constexpr int Bc = 4, Nc = 4096, Dc = 1024, Hc = 16, HDc = 64;

__device__ __forceinline__ uint16_t f2bf(float f) {
  __bf16 h = (__bf16)f;
  return __builtin_bit_cast(uint16_t, h);
}

// async global->LDS, 16B per lane. LDS dest must be wave-uniform base + lane*16.
__device__ __forceinline__ void gload16(const void* g, void* l) {
  __builtin_amdgcn_global_load_lds(
      (__attribute__((address_space(1))) void*)(g),
      (__attribute__((address_space(3))) void*)(l), 16, 0, 0);
}

// ---------------------------------------------------------------------------
// f32 -> bf16 convert (vectorized, 8 elems/thread). n must be a multiple of 8.
// ---------------------------------------------------------------------------
__global__ __launch_bounds__(256) void cvt_f32_bf16(
    const float* __restrict__ src, uint16_t* __restrict__ dst, int n) {
  const int i = (blockIdx.x * 256 + threadIdx.x) * 8;
  if (i >= n) return;
  const float4 a = *(const float4*)(src + i);
  const float4 b = *(const float4*)(src + i + 4);
  union { uint16_t u[8]; uint4 v; } o;
  o.u[0] = f2bf(a.x); o.u[1] = f2bf(a.y); o.u[2] = f2bf(a.z); o.u[3] = f2bf(a.w);
  o.u[4] = f2bf(b.x); o.u[5] = f2bf(b.y); o.u[6] = f2bf(b.z); o.u[7] = f2bf(b.w);
  *(uint4*)(dst + i) = o.v;
}

// ---------------------------------------------------------------------------
// BT-GEMM: C[m, e] = sum_k A[m, k] * Bw[e, k].  128x128 tile, BK=64, 4 waves.
// EPI=0: QKV projection epilogue -> RoPE (f32 rot) -> Q/K [B,H,N,HD] bf16,
//        Q pre-scaled by 0.125*log2(e) (exp2-domain softmax),
//        V transposed [B,H,HD,N] bf16
// EPI=1: bias add (f32) -> Out [M, 1024] f32
// ---------------------------------------------------------------------------
template <int EPI>
__global__ __launch_bounds__(256, 2) void gemm_bt(
    const uint16_t* __restrict__ A, const uint16_t* __restrict__ Bw, int K,
    const float* __restrict__ rot, uint16_t* __restrict__ Qb,
    uint16_t* __restrict__ Kb, uint16_t* __restrict__ Vg,
    const float* __restrict__ bias, float* __restrict__ Out) {
  __shared__ __align__(16) uint16_t As[128 * 64];
  __shared__ __align__(16) uint16_t Bs[128 * 64];
  const int tid = threadIdx.x;
  const int lane = tid & 63, wave = tid >> 6;
  const int l15 = lane & 15, g = lane >> 4;
  const int wr = wave >> 1, wc = wave & 1;
  const int m0 = blockIdx.y * 128;
  const int n0 = blockIdx.x * 128;

  f32x4 acc[4][4];
  const f32x4 fz = {0.f, 0.f, 0.f, 0.f};
#pragma unroll
  for (int i = 0; i < 4; ++i)
#pragma unroll
    for (int j = 0; j < 4; ++j) acc[i][j] = fz;

  for (int kt = 0; kt < K; kt += 64) {
    __syncthreads();  // previous iter's LDS reads done before overwrite
#pragma unroll
    for (int i = 0; i < 4; ++i) {
      const int chunk = tid + i * 256;  // 0..1023 : 128 rows x 8 chunks(16B)
      const int r = chunk >> 3, c = chunk & 7;
      const int cs = c ^ (r & 7);  // pre-swizzled source (linear LDS dest)
      gload16(A + (size_t)(m0 + r) * K + kt + cs * 8, &As[chunk * 8]);
      gload16(Bw + (size_t)(n0 + r) * K + kt + cs * 8, &Bs[chunk * 8]);
    }
    __syncthreads();  // implies vmcnt(0): staged data visible

    bf16x8 af[4][2], bfr[4][2];
#pragma unroll
    for (int mi = 0; mi < 4; ++mi)
#pragma unroll
      for (int kk = 0; kk < 2; ++kk) {
        const int r = wr * 64 + mi * 16 + l15;
        const int ca = (kk * 4 + g) ^ (r & 7);
        af[mi][kk] = *(const bf16x8*)((const char*)As + r * 128 + ca * 16);
        const int r2 = wc * 64 + mi * 16 + l15;
        const int cb = (kk * 4 + g) ^ (r2 & 7);
        bfr[mi][kk] = *(const bf16x8*)((const char*)Bs + r2 * 128 + cb * 16);
      }
#pragma unroll
    for (int mi = 0; mi < 4; ++mi)
#pragma unroll
      for (int nj = 0; nj < 4; ++nj)
#pragma unroll
        for (int kk = 0; kk < 2; ++kk)
          acc[mi][nj] = MFMA16(af[mi][kk], bfr[nj][kk], acc[mi][nj]);
  }

  if (EPI == 0) {
    // C rows m -> (b, n); cols e -> (part, h, hd). RoPE pair is lane^1.
    const int b = m0 >> 12;  // 4096 rows per batch, 128 | 4096 -> uniform
#pragma unroll
    for (int nj = 0; nj < 4; ++nj) {
      const int e = n0 + wc * 64 + nj * 16 + l15;
      const int part = e >> 10;           // wave-uniform (16-col tile)
      const int d = e & 1023;
      const int h = d >> 6, hd = d & 63;
      // exp2-domain: fold 0.125*log2(e) into Q
      const float sc = (part == 0) ? 0.18033688011112042f : 1.0f;
#pragma unroll
      for (int mi = 0; mi < 4; ++mi) {
        if (part == 2) {
          // V transposed: [B, H, HD, N]; pack 4 consecutive n into 8B store
          const int nb = (m0 & 4095) + wr * 64 + mi * 16 + g * 4;
          uint2 pv;
          pv.x = (uint32_t)f2bf(acc[mi][nj][0]) |
                 ((uint32_t)f2bf(acc[mi][nj][1]) << 16);
          pv.y = (uint32_t)f2bf(acc[mi][nj][2]) |
                 ((uint32_t)f2bf(acc[mi][nj][3]) << 16);
          *(uint2*)(Vg + ((size_t)(b * Hc + h) * HDc + hd) * Nc + nb) = pv;
        } else {
          uint16_t* dst = (part == 0) ? Qb : Kb;
          const size_t base = ((size_t)(b * Hc + h) * Nc) * HDc + hd;
#pragma unroll
          for (int rg = 0; rg < 4; ++rg) {
            const int m = m0 + wr * 64 + mi * 16 + g * 4 + rg;
            const int n = m & (Nc - 1);
            const float val = acc[mi][nj][rg];
            const float partner = __shfl_xor(val, 1);
            const float x2 = (e & 1) ? partner : -partner;
            const float2 cs =
                *(const float2*)(rot + ((size_t)(b * Nc + n) * Dc + d) * 2);
            dst[base + (size_t)n * HDc] = f2bf((val * cs.x + x2 * cs.y) * sc);
          }
        }
      }
    }
  } else {
#pragma unroll
    for (int nj = 0; nj < 4; ++nj) {
      const int e = n0 + wc * 64 + nj * 16 + l15;
      const float bia = bias[e];
#pragma unroll
      for (int mi = 0; mi < 4; ++mi)
#pragma unroll
        for (int rg = 0; rg < 4; ++rg) {
          const int m = m0 + wr * 64 + mi * 16 + g * 4 + rg;
          Out[(size_t)m * Dc + e] = acc[mi][nj][rg] + bia;
        }
    }
  }
}

// ---------------------------------------------------------------------------
// Flash attention, swapped-QK + swapped-PV, exp2-domain softmax, runtime
// double-buffer (r4-proven structure: inline body, no lambda-captured arrays),
// chunk-XOR swizzled P tile, defer-rescale (T13), setprio (T5), and the
// softmax denominator computed by ones-vector MFMA (cross-g sum in-MFMA).
// ---------------------------------------------------------------------------
__global__ __launch_bounds__(256, 3) void attn_fa(
    const uint16_t* __restrict__ Qb, const uint16_t* __restrict__ Kb,
    const uint16_t* __restrict__ Vg, uint16_t* __restrict__ Ob) {
  __shared__ __align__(16) uint16_t Ks[2][64 * 64];  // [kv][d], chunk-swizzled
  __shared__ __align__(16) uint16_t Vt[2][64 * 64];  // [d][kv], chunk-swizzled
  __shared__ __align__(16) uint16_t Pl[4][16 * 64];  // per-wave P [q][kv], swz
  const int tid = threadIdx.x;
  const int lane = tid & 63, wave = tid >> 6;
  const int l15 = lane & 15, g = lane >> 4;
  const int swz = l15 & 7;
  const int bh = blockIdx.y;
  const int q0 = blockIdx.x * 128;
  const size_t bhN = (size_t)bh * Nc;
  const size_t bhHD = (size_t)bh * HDc;
  char* plw = (char*)&Pl[wave][0] + l15 * 128;  // this lane's q-row base

  // Q fragments register-resident for the whole block (B-operand layout)
  bf16x8 qf[2][2];
#pragma unroll
  for (int rf = 0; rf < 2; ++rf)
#pragma unroll
    for (int kk = 0; kk < 2; ++kk)
      qf[rf][kk] = *(const bf16x8*)(Qb + (bhN + q0 + wave * 32 + rf * 16 + l15) * HDc +
                                    kk * 32 + g * 8);

  // all-ones A-fragment for the denominator MFMA
  bf16x8 onef;
#pragma unroll
  for (int j = 0; j < 8; ++j) onef[j] = (__bf16)1.0f;

  const f32x4 fz = {0.f, 0.f, 0.f, 0.f};
  f32x4 O[2][4];
  float mrow[2] = {-1e30f, -1e30f}, lrow[2] = {0.f, 0.f};
#pragma unroll
  for (int rf = 0; rf < 2; ++rf)
#pragma unroll
    for (int df = 0; df < 4; ++df) O[rf][df] = fz;

  // stage K/V tile t into given LDS buffers (linear dest, pre-swz source)
  auto stage = [&](uint16_t* ksd, uint16_t* vtd, int t) {
    const int kv0 = t * 64;
#pragma unroll
    for (int i = 0; i < 2; ++i) {
      const int ch = tid + i * 256;  // 0..511 : 64 rows x 8 chunks(16B)
      const int r = ch >> 3, c = ch & 7;
      const int cs = c ^ (r & 7);
      gload16(Kb + (bhN + kv0 + r) * HDc + cs * 8, ksd + ch * 8);
      gload16(Vg + (bhHD + r) * Nc + kv0 + cs * 8, vtd + ch * 8);
    }
  };

  stage(Ks[0], Vt[0], 0);
  int cur = 0;
  for (int t = 0; t < Nc / 64; ++t) {
    __syncthreads();  // drains vmcnt: tile t visible; prev iter's reads closed
    if (t < Nc / 64 - 1) stage(Ks[cur ^ 1], Vt[cur ^ 1], t + 1);

    const uint16_t* ks = &Ks[cur][0];
    const uint16_t* vt = &Vt[cur][0];

    // St[rf][cf]: lane(g,l15) reg r4 = S'[q=l15+rf*16][kv=cf*16+g*4+r4]
    f32x4 St[2][4];
#pragma unroll
    for (int rf = 0; rf < 2; ++rf)
#pragma unroll
      for (int cf = 0; cf < 4; ++cf) St[rf][cf] = fz;
    __builtin_amdgcn_s_setprio(1);
#pragma unroll
    for (int cf = 0; cf < 4; ++cf)
#pragma unroll
      for (int kk = 0; kk < 2; ++kk) {
        bf16x8 kf = *(const bf16x8*)(&ks[(cf * 16 + l15) * 64 + ((kk * 4 + g) ^ swz) * 8]);
        St[0][cf] = MFMA16(kf, qf[0][kk], St[0][cf]);
        St[1][cf] = MFMA16(kf, qf[1][kk], St[1][cf]);
      }
    __builtin_amdgcn_s_setprio(0);

    // V fragments (A-operand: row = d = df*16+l15)
    bf16x8 vb[4][2];
#pragma unroll
    for (int df = 0; df < 4; ++df) {
      vb[df][0] = *(const bf16x8*)(&vt[(df * 16 + l15) * 64 + (g ^ swz) * 8]);
      vb[df][1] = *(const bf16x8*)(&vt[(df * 16 + l15) * 64 + ((4 + g) ^ swz) * 8]);
    }

#pragma unroll
    for (int rf = 0; rf < 2; ++rf) {
      // tile max (tree) then combine 4 g-groups
      f32x4 m01, m23;
#pragma unroll
      for (int j = 0; j < 4; ++j) {
        m01[j] = fmaxf(St[rf][0][j], St[rf][1][j]);
        m23[j] = fmaxf(St[rf][2][j], St[rf][3][j]);
      }
      float pm = fmaxf(fmaxf(fmaxf(m01[0], m01[1]), fmaxf(m01[2], m01[3])),
                       fmaxf(fmaxf(m23[0], m23[1]), fmaxf(m23[2], m23[3])));
      pm = fmaxf(pm, __shfl_xor(pm, 16));
      pm = fmaxf(pm, __shfl_xor(pm, 32));

      // defer-rescale (exp2 domain): only pay the O-pass when max grew >11.5
      if (__any(pm > mrow[rf] + 11.5f)) {
        const float mN = fmaxf(mrow[rf], pm);
        const float corr = exp2f(mrow[rf] - mN);
        mrow[rf] = mN;
        lrow[rf] *= corr;
#pragma unroll
        for (int df = 0; df < 4; ++df)
#pragma unroll
          for (int r4 = 0; r4 < 4; ++r4) O[rf][df][r4] *= corr;
      }
      const float mN = mrow[rf];

#pragma unroll
      for (int cf = 0; cf < 4; ++cf)
#pragma unroll
        for (int r4 = 0; r4 < 4; ++r4) St[rf][cf][r4] = exp2f(St[rf][cf][r4] - mN);

      // P pack into chunk-XOR swizzled [q][kv] tile: elem (q,kv) at byte
      // q*128 + ((kv>>3)^(q&7))*16 + (kv&7)*2. Lane writes kv=cf*16+g*4+r4.
#pragma unroll
      for (int cf = 0; cf < 4; ++cf) {
        uint2 pv;
        pv.x = (uint32_t)f2bf(St[rf][cf][0]) | ((uint32_t)f2bf(St[rf][cf][1]) << 16);
        pv.y = (uint32_t)f2bf(St[rf][cf][2]) | ((uint32_t)f2bf(St[rf][cf][3]) << 16);
        *(uint2*)(plw + (((cf * 2 + (g >> 1)) ^ swz) * 16) + (g & 1) * 8) = pv;
      }

      // P fragments (B-operand: col = q = l15, 8 contiguous kv per lane)
      bf16x8 pa0 = *(const bf16x8*)(plw + ((g ^ swz) * 16));
      bf16x8 pa1 = *(const bf16x8*)(plw + (((4 + g) ^ swz) * 16));

      // denominator via ones-MFMA: sums ALL 64 kv (cross-g) in-pipe, in-lane
      f32x4 ls = fz;
      __builtin_amdgcn_s_setprio(1);
      ls = MFMA16(onef, pa0, ls);
      ls = MFMA16(onef, pa1, ls);
      // PV with swapped args: Ot[col=q=l15][row=d] = mfma(V-frag, P-frag)
#pragma unroll
      for (int df = 0; df < 4; ++df) {
        O[rf][df] = MFMA16(vb[df][0], pa0, O[rf][df]);
        O[rf][df] = MFMA16(vb[df][1], pa1, O[rf][df]);
      }
      __builtin_amdgcn_s_setprio(0);
      lrow[rf] += ls[0];
    }
    cur ^= 1;
  }

  // epilogue: per-lane normalize (q = l15), packed 8B stores
  const int b = bh >> 4, h = bh & 15;
#pragma unroll
  for (int rf = 0; rf < 2; ++rf) {
    const float inv = 1.f / lrow[rf];
    const int n = q0 + wave * 32 + rf * 16 + l15;
    uint16_t* orow = Ob + ((size_t)b * Nc + n) * Dc + h * HDc;
#pragma unroll
    for (int df = 0; df < 4; ++df) {
      uint2 pv;
      pv.x = (uint32_t)f2bf(O[rf][df][0] * inv) |
             ((uint32_t)f2bf(O[rf][df][1] * inv) << 16);
      pv.y = (uint32_t)f2bf(O[rf][df][2] * inv) |
             ((uint32_t)f2bf(O[rf][df][3] * inv) << 16);
      *(uint2*)(orow + df * 16 + g * 4) = pv;
    }
  }
}

extern "C" void kernel_launch(void* const* d_in, const int* in_sizes, int n_in,
                              void* d_out, int out_size, void* d_ws, size_t ws_size,
                              hipStream_t stream) {
  const float* x = (const float*)d_in[0];      // [B,N,D] f32
  const float* rot = (const float*)d_in[1];    // [B,N,D,2] f32
  const float* Wqkv = (const float*)d_in[2];   // [3D,D] f32
  const float* Wout = (const float*)d_in[3];   // [D,D] f32
  const float* bout = (const float*)d_in[4];   // [D] f32
  float* out = (float*)d_out;                  // [B,N,D] f32

  uint16_t* ws = (uint16_t*)d_ws;
  const size_t XSZ = (size_t)Bc * Nc * Dc;        // 16,777,216 elems
  const size_t W1SZ = (size_t)3 * Dc * Dc;        //  3,145,728
  const size_t W2SZ = (size_t)Dc * Dc;            //  1,048,576
  uint16_t* xb = ws;               // bf16 x; ALIASED with At (safe: xb's last
  uint16_t* At = ws;               // read is gemm1; At first written by attn)
  uint16_t* Qb = ws + XSZ;
  uint16_t* Kb = ws + 2 * XSZ;
  uint16_t* Vg = ws + 3 * XSZ;     // transposed [B,H,HD,N]
  uint16_t* Wqb = ws + 4 * XSZ;
  uint16_t* Wob = ws + 4 * XSZ + W1SZ;
  // total: 4*XSZ + W1SZ + W2SZ = 71,303,168 elems = 142.6 MB

  dim3 blk(256);
  cvt_f32_bf16<<<dim3((XSZ / 8 + 255) / 256), blk, 0, stream>>>(x, xb, (int)XSZ);
  cvt_f32_bf16<<<dim3((W1SZ / 8 + 255) / 256), blk, 0, stream>>>(Wqkv, Wqb, (int)W1SZ);
  cvt_f32_bf16<<<dim3((W2SZ / 8 + 255) / 256), blk, 0, stream>>>(Wout, Wob, (int)W2SZ);

  gemm_bt<0><<<dim3((3 * Dc) / 128, (Bc * Nc) / 128), blk, 0, stream>>>(
      xb, Wqb, Dc, rot, Qb, Kb, Vg, nullptr, nullptr);
  attn_fa<<<dim3(Nc / 128, Bc * Hc), blk, 0, stream>>>(Qb, Kb, Vg, At);
  gemm_bt<1><<<dim3(Dc / 128, (Bc * Nc) / 128), blk, 0, stream>>>(
      At, Wob, Dc, nullptr, nullptr, nullptr, nullptr, bout, out);
}

// Round 7
// 741.128 us; speedup vs baseline: 1.6407x; 1.0750x over previous
//
#include <hip/hip_runtime.h>
#include <hip/hip_bf16.h>
#include <stdint.h>
#include <stddef.h>

typedef __attribute__((ext_vector_type(8))) __bf16 bf16x8;
typedef __attribute__((ext_vector_type(4))) float f32x4;

#define MFMA16(a, b, c) __builtin_amdgcn_mfma_f32_16x16x32_bf16((a), (b), (c), 0, 0, 0)

static constexpr int Bc = 4, Nc = 4096, Dc = 1024, Hc = 16, HDc = 64;

__device__ __forceinline__ uint16_t f2bf(float f) {
  __bf16 h = (__bf16)f;
  return __builtin_bit_cast(uint16_t, h);
}

// raw v_exp_f32 (no libm edge-case code; inputs here are finite and <= 0)
__device__ __forceinline__ float fexp2(float x) {
#if __has_builtin(__builtin_amdgcn_exp2f)
  return __builtin_amdgcn_exp2f(x);
#else
  return __builtin_exp2f(x);
#endif
}

// async global->LDS, 16B per lane. LDS dest must be wave-uniform base + lane*16.
__device__ __forceinline__ void gload16(const void* g, void* l) {
  __builtin_amdgcn_global_load_lds(
      (__attribute__((address_space(1))) void*)(g),
      (__attribute__((address_space(3))) void*)(l), 16, 0, 0);
}

// ---------------------------------------------------------------------------
// f32 -> bf16 convert (vectorized, 8 elems/thread). n must be a multiple of 8.
// ---------------------------------------------------------------------------
__global__ __launch_bounds__(256) void cvt_f32_bf16(
    const float* __restrict__ src, uint16_t* __restrict__ dst, int n) {
  const int i = (blockIdx.x * 256 + threadIdx.x) * 8;
  if (i >= n) return;
  const float4 a = *(const float4*)(src + i);
  const float4 b = *(const float4*)(src + i + 4);
  union { uint16_t u[8]; uint4 v; } o;
  o.u[0] = f2bf(a.x); o.u[1] = f2bf(a.y); o.u[2] = f2bf(a.z); o.u[3] = f2bf(a.w);
  o.u[4] = f2bf(b.x); o.u[5] = f2bf(b.y); o.u[6] = f2bf(b.z); o.u[7] = f2bf(b.w);
  *(uint4*)(dst + i) = o.v;
}

// ---------------------------------------------------------------------------
// BT-GEMM: C[m, e] = sum_k A[m, k] * Bw[e, k].  128x128 tile, BK=64, 4 waves.
// EPI=0: QKV projection epilogue -> RoPE (f32 rot) -> Q/K [B,H,N,HD] bf16,
//        Q pre-scaled by 0.125*log2(e) (exp2-domain softmax),
//        V transposed [B,H,HD,N] bf16
// EPI=1: bias add (f32) -> Out [M, 1024] f32
// ---------------------------------------------------------------------------
template <int EPI>
__global__ __launch_bounds__(256, 2) void gemm_bt(
    const uint16_t* __restrict__ A, const uint16_t* __restrict__ Bw, int K,
    const float* __restrict__ rot, uint16_t* __restrict__ Qb,
    uint16_t* __restrict__ Kb, uint16_t* __restrict__ Vg,
    const float* __restrict__ bias, float* __restrict__ Out) {
  __shared__ __align__(16) uint16_t As[128 * 64];
  __shared__ __align__(16) uint16_t Bs[128 * 64];
  const int tid = threadIdx.x;
  const int lane = tid & 63, wave = tid >> 6;
  const int l15 = lane & 15, g = lane >> 4;
  const int wr = wave >> 1, wc = wave & 1;
  const int m0 = blockIdx.y * 128;
  const int n0 = blockIdx.x * 128;

  f32x4 acc[4][4];
  const f32x4 fz = {0.f, 0.f, 0.f, 0.f};
#pragma unroll
  for (int i = 0; i < 4; ++i)
#pragma unroll
    for (int j = 0; j < 4; ++j) acc[i][j] = fz;

  for (int kt = 0; kt < K; kt += 64) {
    __syncthreads();  // previous iter's LDS reads done before overwrite
#pragma unroll
    for (int i = 0; i < 4; ++i) {
      const int chunk = tid + i * 256;  // 0..1023 : 128 rows x 8 chunks(16B)
      const int r = chunk >> 3, c = chunk & 7;
      const int cs = c ^ (r & 7);  // pre-swizzled source (linear LDS dest)
      gload16(A + (size_t)(m0 + r) * K + kt + cs * 8, &As[chunk * 8]);
      gload16(Bw + (size_t)(n0 + r) * K + kt + cs * 8, &Bs[chunk * 8]);
    }
    __syncthreads();  // implies vmcnt(0): staged data visible

    bf16x8 af[4][2], bfr[4][2];
#pragma unroll
    for (int mi = 0; mi < 4; ++mi)
#pragma unroll
      for (int kk = 0; kk < 2; ++kk) {
        const int r = wr * 64 + mi * 16 + l15;
        const int ca = (kk * 4 + g) ^ (r & 7);
        af[mi][kk] = *(const bf16x8*)((const char*)As + r * 128 + ca * 16);
        const int r2 = wc * 64 + mi * 16 + l15;
        const int cb = (kk * 4 + g) ^ (r2 & 7);
        bfr[mi][kk] = *(const bf16x8*)((const char*)Bs + r2 * 128 + cb * 16);
      }
#pragma unroll
    for (int mi = 0; mi < 4; ++mi)
#pragma unroll
      for (int nj = 0; nj < 4; ++nj)
#pragma unroll
        for (int kk = 0; kk < 2; ++kk)
          acc[mi][nj] = MFMA16(af[mi][kk], bfr[nj][kk], acc[mi][nj]);
  }

  if (EPI == 0) {
    // C rows m -> (b, n); cols e -> (part, h, hd). RoPE pair is lane^1.
    const int b = m0 >> 12;  // 4096 rows per batch, 128 | 4096 -> uniform
#pragma unroll
    for (int nj = 0; nj < 4; ++nj) {
      const int e = n0 + wc * 64 + nj * 16 + l15;
      const int part = e >> 10;           // wave-uniform (16-col tile)
      const int d = e & 1023;
      const int h = d >> 6, hd = d & 63;
      // exp2-domain: fold 0.125*log2(e) into Q
      const float sc = (part == 0) ? 0.18033688011112042f : 1.0f;
#pragma unroll
      for (int mi = 0; mi < 4; ++mi) {
        if (part == 2) {
          // V transposed: [B, H, HD, N]; pack 4 consecutive n into 8B store
          const int nb = (m0 & 4095) + wr * 64 + mi * 16 + g * 4;
          uint2 pv;
          pv.x = (uint32_t)f2bf(acc[mi][nj][0]) |
                 ((uint32_t)f2bf(acc[mi][nj][1]) << 16);
          pv.y = (uint32_t)f2bf(acc[mi][nj][2]) |
                 ((uint32_t)f2bf(acc[mi][nj][3]) << 16);
          *(uint2*)(Vg + ((size_t)(b * Hc + h) * HDc + hd) * Nc + nb) = pv;
        } else {
          uint16_t* dst = (part == 0) ? Qb : Kb;
          const size_t base = ((size_t)(b * Hc + h) * Nc) * HDc + hd;
#pragma unroll
          for (int rg = 0; rg < 4; ++rg) {
            const int m = m0 + wr * 64 + mi * 16 + g * 4 + rg;
            const int n = m & (Nc - 1);
            const float val = acc[mi][nj][rg];
            const float partner = __shfl_xor(val, 1);
            const float x2 = (e & 1) ? partner : -partner;
            const float2 cs =
                *(const float2*)(rot + ((size_t)(b * Nc + n) * Dc + d) * 2);
            dst[base + (size_t)n * HDc] = f2bf((val * cs.x + x2 * cs.y) * sc);
          }
        }
      }
    }
  } else {
#pragma unroll
    for (int nj = 0; nj < 4; ++nj) {
      const int e = n0 + wc * 64 + nj * 16 + l15;
      const float bia = bias[e];
#pragma unroll
      for (int mi = 0; mi < 4; ++mi)
#pragma unroll
        for (int rg = 0; rg < 4; ++rg) {
          const int m = m0 + wr * 64 + mi * 16 + g * 4 + rg;
          Out[(size_t)m * Dc + e] = acc[mi][nj][rg] + bia;
        }
    }
  }
}

// ---------------------------------------------------------------------------
// Flash attention, swapped-QK + swapped-PV, exp2-domain softmax (raw
// v_exp_f32), runtime double-buffer, chunk-XOR swizzled P tile,
// defer-rescale (T13), setprio (T5), ones-MFMA softmax denominator.
// LDS 40KB x 4 blocks = 160KB/CU exactly; VGPR 76 < 128 cap for 16 waves/CU.
// ---------------------------------------------------------------------------
__global__ __launch_bounds__(256, 4) void attn_fa(
    const uint16_t* __restrict__ Qb, const uint16_t* __restrict__ Kb,
    const uint16_t* __restrict__ Vg, uint16_t* __restrict__ Ob) {
  __shared__ __align__(16) uint16_t Ks[2][64 * 64];  // [kv][d], chunk-swizzled
  __shared__ __align__(16) uint16_t Vt[2][64 * 64];  // [d][kv], chunk-swizzled
  __shared__ __align__(16) uint16_t Pl[4][16 * 64];  // per-wave P [q][kv], swz
  const int tid = threadIdx.x;
  const int lane = tid & 63, wave = tid >> 6;
  const int l15 = lane & 15, g = lane >> 4;
  const int swz = l15 & 7;
  const int bh = blockIdx.y;
  const int q0 = blockIdx.x * 128;
  const size_t bhN = (size_t)bh * Nc;
  const size_t bhHD = (size_t)bh * HDc;
  char* plw = (char*)&Pl[wave][0] + l15 * 128;  // this lane's q-row base

  // Q fragments register-resident for the whole block (B-operand layout)
  bf16x8 qf[2][2];
#pragma unroll
  for (int rf = 0; rf < 2; ++rf)
#pragma unroll
    for (int kk = 0; kk < 2; ++kk)
      qf[rf][kk] = *(const bf16x8*)(Qb + (bhN + q0 + wave * 32 + rf * 16 + l15) * HDc +
                                    kk * 32 + g * 8);

  // all-ones A-fragment for the denominator MFMA
  bf16x8 onef;
#pragma unroll
  for (int j = 0; j < 8; ++j) onef[j] = (__bf16)1.0f;

  const f32x4 fz = {0.f, 0.f, 0.f, 0.f};
  f32x4 O[2][4];
  float mrow[2] = {-1e30f, -1e30f}, lrow[2] = {0.f, 0.f};
#pragma unroll
  for (int rf = 0; rf < 2; ++rf)
#pragma unroll
    for (int df = 0; df < 4; ++df) O[rf][df] = fz;

  // stage K/V tile t into given LDS buffers (linear dest, pre-swz source)
  auto stage = [&](uint16_t* ksd, uint16_t* vtd, int t) {
    const int kv0 = t * 64;
#pragma unroll
    for (int i = 0; i < 2; ++i) {
      const int ch = tid + i * 256;  // 0..511 : 64 rows x 8 chunks(16B)
      const int r = ch >> 3, c = ch & 7;
      const int cs = c ^ (r & 7);
      gload16(Kb + (bhN + kv0 + r) * HDc + cs * 8, ksd + ch * 8);
      gload16(Vg + (bhHD + r) * Nc + kv0 + cs * 8, vtd + ch * 8);
    }
  };

  stage(Ks[0], Vt[0], 0);
  int cur = 0;
  for (int t = 0; t < Nc / 64; ++t) {
    __syncthreads();  // drains vmcnt: tile t visible; prev iter's reads closed
    if (t < Nc / 64 - 1) stage(Ks[cur ^ 1], Vt[cur ^ 1], t + 1);

    const uint16_t* ks = &Ks[cur][0];
    const uint16_t* vt = &Vt[cur][0];

    // St[rf][cf]: lane(g,l15) reg r4 = S'[q=l15+rf*16][kv=cf*16+g*4+r4]
    f32x4 St[2][4];
#pragma unroll
    for (int rf = 0; rf < 2; ++rf)
#pragma unroll
      for (int cf = 0; cf < 4; ++cf) St[rf][cf] = fz;
    __builtin_amdgcn_s_setprio(1);
#pragma unroll
    for (int cf = 0; cf < 4; ++cf)
#pragma unroll
      for (int kk = 0; kk < 2; ++kk) {
        bf16x8 kf = *(const bf16x8*)(&ks[(cf * 16 + l15) * 64 + ((kk * 4 + g) ^ swz) * 8]);
        St[0][cf] = MFMA16(kf, qf[0][kk], St[0][cf]);
        St[1][cf] = MFMA16(kf, qf[1][kk], St[1][cf]);
      }
    __builtin_amdgcn_s_setprio(0);

    // V fragments (A-operand: row = d = df*16+l15)
    bf16x8 vb[4][2];
#pragma unroll
    for (int df = 0; df < 4; ++df) {
      vb[df][0] = *(const bf16x8*)(&vt[(df * 16 + l15) * 64 + (g ^ swz) * 8]);
      vb[df][1] = *(const bf16x8*)(&vt[(df * 16 + l15) * 64 + ((4 + g) ^ swz) * 8]);
    }

#pragma unroll
    for (int rf = 0; rf < 2; ++rf) {
      // tile max (tree) then combine 4 g-groups
      f32x4 m01, m23;
#pragma unroll
      for (int j = 0; j < 4; ++j) {
        m01[j] = fmaxf(St[rf][0][j], St[rf][1][j]);
        m23[j] = fmaxf(St[rf][2][j], St[rf][3][j]);
      }
      float pm = fmaxf(fmaxf(fmaxf(m01[0], m01[1]), fmaxf(m01[2], m01[3])),
                       fmaxf(fmaxf(m23[0], m23[1]), fmaxf(m23[2], m23[3])));
      pm = fmaxf(pm, __shfl_xor(pm, 16));
      pm = fmaxf(pm, __shfl_xor(pm, 32));

      // defer-rescale (exp2 domain): only pay the O-pass when max grew >11.5
      if (__any(pm > mrow[rf] + 11.5f)) {
        const float mN = fmaxf(mrow[rf], pm);
        const float corr = fexp2(mrow[rf] - mN);
        mrow[rf] = mN;
        lrow[rf] *= corr;
#pragma unroll
        for (int df = 0; df < 4; ++df)
#pragma unroll
          for (int r4 = 0; r4 < 4; ++r4) O[rf][df][r4] *= corr;
      }
      const float mN = mrow[rf];

#pragma unroll
      for (int cf = 0; cf < 4; ++cf)
#pragma unroll
        for (int r4 = 0; r4 < 4; ++r4) St[rf][cf][r4] = fexp2(St[rf][cf][r4] - mN);

      // P pack into chunk-XOR swizzled [q][kv] tile: elem (q,kv) at byte
      // q*128 + ((kv>>3)^(q&7))*16 + (kv&7)*2. Lane writes kv=cf*16+g*4+r4.
#pragma unroll
      for (int cf = 0; cf < 4; ++cf) {
        uint2 pv;
        pv.x = (uint32_t)f2bf(St[rf][cf][0]) | ((uint32_t)f2bf(St[rf][cf][1]) << 16);
        pv.y = (uint32_t)f2bf(St[rf][cf][2]) | ((uint32_t)f2bf(St[rf][cf][3]) << 16);
        *(uint2*)(plw + (((cf * 2 + (g >> 1)) ^ swz) * 16) + (g & 1) * 8) = pv;
      }

      // P fragments (B-operand: col = q = l15, 8 contiguous kv per lane)
      bf16x8 pa0 = *(const bf16x8*)(plw + ((g ^ swz) * 16));
      bf16x8 pa1 = *(const bf16x8*)(plw + (((4 + g) ^ swz) * 16));

      // denominator via ones-MFMA: sums ALL 64 kv (cross-g) in-pipe, in-lane
      f32x4 ls = fz;
      __builtin_amdgcn_s_setprio(1);
      ls = MFMA16(onef, pa0, ls);
      ls = MFMA16(onef, pa1, ls);
      // PV with swapped args: Ot[col=q=l15][row=d] = mfma(V-frag, P-frag)
#pragma unroll
      for (int df = 0; df < 4; ++df) {
        O[rf][df] = MFMA16(vb[df][0], pa0, O[rf][df]);
        O[rf][df] = MFMA16(vb[df][1], pa1, O[rf][df]);
      }
      __builtin_amdgcn_s_setprio(0);
      lrow[rf] += ls[0];
    }
    cur ^= 1;
  }

  // epilogue: per-lane normalize (q = l15), packed 8B stores
  const int b = bh >> 4, h = bh & 15;
#pragma unroll
  for (int rf = 0; rf < 2; ++rf) {
    const float inv = 1.f / lrow[rf];
    const int n = q0 + wave * 32 + rf * 16 + l15;
    uint16_t* orow = Ob + ((size_t)b * Nc + n) * Dc + h * HDc;
#pragma unroll
    for (int df = 0; df < 4; ++df) {
      uint2 pv;
      pv.x = (uint32_t)f2bf(O[rf][df][0] * inv) |
             ((uint32_t)f2bf(O[rf][df][1] * inv) << 16);
      pv.y = (uint32_t)f2bf(O[rf][df][2] * inv) |
             ((uint32_t)f2bf(O[rf][df][3] * inv) << 16);
      *(uint2*)(orow + df * 16 + g * 4) = pv;
    }
  }
}

extern "C" void kernel_launch(void* const* d_in, const int* in_sizes, int n_in,
                              void* d_out, int out_size, void* d_ws, size_t ws_size,
                              hipStream_t stream) {
  const float* x = (const float*)d_in[0];      // [B,N,D] f32
  const float* rot = (const float*)d_in[1];    // [B,N,D,2] f32
  const float* Wqkv = (const float*)d_in[2];   // [3D,D] f32
  const float* Wout = (const float*)d_in[3];   // [D,D] f32
  const float* bout = (const float*)d_in[4];   // [D] f32
  float* out = (float*)d_out;                  // [B,N,D] f32

  uint16_t* ws = (uint16_t*)d_ws;
  const size_t XSZ = (size_t)Bc * Nc * Dc;        // 16,777,216 elems
  const size_t W1SZ = (size_t)3 * Dc * Dc;        //  3,145,728
  const size_t W2SZ = (size_t)Dc * Dc;            //  1,048,576
  uint16_t* xb = ws;               // bf16 x; ALIASED with At (safe: xb's last
  uint16_t* At = ws;               // read is gemm1; At first written by attn)
  uint16_t* Qb = ws + XSZ;
  uint16_t* Kb = ws + 2 * XSZ;
  uint16_t* Vg = ws + 3 * XSZ;     // transposed [B,H,HD,N]
  uint16_t* Wqb = ws + 4 * XSZ;
  uint16_t* Wob = ws + 4 * XSZ + W1SZ;
  // total: 4*XSZ + W1SZ + W2SZ = 71,303,168 elems = 142.6 MB

  dim3 blk(256);
  cvt_f32_bf16<<<dim3((XSZ / 8 + 255) / 256), blk, 0, stream>>>(x, xb, (int)XSZ);
  cvt_f32_bf16<<<dim3((W1SZ / 8 + 255) / 256), blk, 0, stream>>>(Wqkv, Wqb, (int)W1SZ);
  cvt_f32_bf16<<<dim3((W2SZ / 8 + 255) / 256), blk, 0, stream>>>(Wout, Wob, (int)W2SZ);

  gemm_bt<0><<<dim3((3 * Dc) / 128, (Bc * Nc) / 128), blk, 0, stream>>>(
      xb, Wqb, Dc, rot, Qb, Kb, Vg, nullptr, nullptr);
  attn_fa<<<dim3(Nc / 128, Bc * Hc), blk, 0, stream>>>(Qb, Kb, Vg, At);
  gemm_bt<1><<<dim3(Dc / 128, (Bc * Nc) / 128), blk, 0, stream>>>(
      At, Wob, Dc, nullptr, nullptr, nullptr, nullptr, bout, out);
}

// Round 8
// 659.561 us; speedup vs baseline: 1.8436x; 1.1237x over previous
//
#include <hip/hip_runtime.h>
#include <hip/hip_bf16.h>
#include <stdint.h>
#include <stddef.h>

typedef __attribute__((ext_vector_type(8))) __bf16 bf16x8;
typedef __attribute__((ext_vector_type(4))) float f32x4;

#define MFMA16(a, b, c) __builtin_amdgcn_mfma_f32_16x16x32_bf16((a), (b), (c), 0, 0, 0)

static constexpr int Bc = 4, Nc = 4096, Dc = 1024, Hc = 16, HDc = 64;

__device__ __forceinline__ uint16_t f2bf(float f) {
  __bf16 h = (__bf16)f;
  return __builtin_bit_cast(uint16_t, h);
}

// raw v_exp_f32 (no libm edge-case code; inputs here are finite, bounded)
__device__ __forceinline__ float fexp2(float x) {
#if __has_builtin(__builtin_amdgcn_exp2f)
  return __builtin_amdgcn_exp2f(x);
#else
  return __builtin_exp2f(x);
#endif
}

// async global->LDS, 16B per lane. LDS dest must be wave-uniform base + lane*16.
__device__ __forceinline__ void gload16(const void* g, void* l) {
  __builtin_amdgcn_global_load_lds(
      (__attribute__((address_space(1))) void*)(g),
      (__attribute__((address_space(3))) void*)(l), 16, 0, 0);
}

// ---------------------------------------------------------------------------
// f32 -> bf16 convert (vectorized, 8 elems/thread). n must be a multiple of 8.
// ---------------------------------------------------------------------------
__global__ __launch_bounds__(256) void cvt_f32_bf16(
    const float* __restrict__ src, uint16_t* __restrict__ dst, int n) {
  const int i = (blockIdx.x * 256 + threadIdx.x) * 8;
  if (i >= n) return;
  const float4 a = *(const float4*)(src + i);
  const float4 b = *(const float4*)(src + i + 4);
  union { uint16_t u[8]; uint4 v; } o;
  o.u[0] = f2bf(a.x); o.u[1] = f2bf(a.y); o.u[2] = f2bf(a.z); o.u[3] = f2bf(a.w);
  o.u[4] = f2bf(b.x); o.u[5] = f2bf(b.y); o.u[6] = f2bf(b.z); o.u[7] = f2bf(b.w);
  *(uint4*)(dst + i) = o.v;
}

// ---------------------------------------------------------------------------
// BT-GEMM: C[m, e] = sum_k A[m, k] * Bw[e, k].  128x128 tile, BK=64, 4 waves.
// EPI=0: QKV projection epilogue -> RoPE (f32 rot) -> Q/K [B,H,N,HD] bf16,
//        Q pre-scaled by 0.125*log2(e) (exp2-domain softmax),
//        V transposed [B,H,HD,N] bf16
// EPI=1: bias add (f32) -> Out [M, 1024] f32
// ---------------------------------------------------------------------------
template <int EPI>
__global__ __launch_bounds__(256, 2) void gemm_bt(
    const uint16_t* __restrict__ A, const uint16_t* __restrict__ Bw, int K,
    const float* __restrict__ rot, uint16_t* __restrict__ Qb,
    uint16_t* __restrict__ Kb, uint16_t* __restrict__ Vg,
    const float* __restrict__ bias, float* __restrict__ Out) {
  __shared__ __align__(16) uint16_t As[128 * 64];
  __shared__ __align__(16) uint16_t Bs[128 * 64];
  const int tid = threadIdx.x;
  const int lane = tid & 63, wave = tid >> 6;
  const int l15 = lane & 15, g = lane >> 4;
  const int wr = wave >> 1, wc = wave & 1;
  const int m0 = blockIdx.y * 128;
  const int n0 = blockIdx.x * 128;

  f32x4 acc[4][4];
  const f32x4 fz = {0.f, 0.f, 0.f, 0.f};
#pragma unroll
  for (int i = 0; i < 4; ++i)
#pragma unroll
    for (int j = 0; j < 4; ++j) acc[i][j] = fz;

  for (int kt = 0; kt < K; kt += 64) {
    __syncthreads();  // previous iter's LDS reads done before overwrite
#pragma unroll
    for (int i = 0; i < 4; ++i) {
      const int chunk = tid + i * 256;  // 0..1023 : 128 rows x 8 chunks(16B)
      const int r = chunk >> 3, c = chunk & 7;
      const int cs = c ^ (r & 7);  // pre-swizzled source (linear LDS dest)
      gload16(A + (size_t)(m0 + r) * K + kt + cs * 8, &As[chunk * 8]);
      gload16(Bw + (size_t)(n0 + r) * K + kt + cs * 8, &Bs[chunk * 8]);
    }
    __syncthreads();  // implies vmcnt(0): staged data visible

    bf16x8 af[4][2], bfr[4][2];
#pragma unroll
    for (int mi = 0; mi < 4; ++mi)
#pragma unroll
      for (int kk = 0; kk < 2; ++kk) {
        const int r = wr * 64 + mi * 16 + l15;
        const int ca = (kk * 4 + g) ^ (r & 7);
        af[mi][kk] = *(const bf16x8*)((const char*)As + r * 128 + ca * 16);
        const int r2 = wc * 64 + mi * 16 + l15;
        const int cb = (kk * 4 + g) ^ (r2 & 7);
        bfr[mi][kk] = *(const bf16x8*)((const char*)Bs + r2 * 128 + cb * 16);
      }
#pragma unroll
    for (int mi = 0; mi < 4; ++mi)
#pragma unroll
      for (int nj = 0; nj < 4; ++nj)
#pragma unroll
        for (int kk = 0; kk < 2; ++kk)
          acc[mi][nj] = MFMA16(af[mi][kk], bfr[nj][kk], acc[mi][nj]);
  }

  if (EPI == 0) {
    // C rows m -> (b, n); cols e -> (part, h, hd). RoPE pair is lane^1.
    const int b = m0 >> 12;  // 4096 rows per batch, 128 | 4096 -> uniform
#pragma unroll
    for (int nj = 0; nj < 4; ++nj) {
      const int e = n0 + wc * 64 + nj * 16 + l15;
      const int part = e >> 10;           // wave-uniform (16-col tile)
      const int d = e & 1023;
      const int h = d >> 6, hd = d & 63;
      // exp2-domain: fold 0.125*log2(e) into Q
      const float sc = (part == 0) ? 0.18033688011112042f : 1.0f;
#pragma unroll
      for (int mi = 0; mi < 4; ++mi) {
        if (part == 2) {
          // V transposed: [B, H, HD, N]; pack 4 consecutive n into 8B store
          const int nb = (m0 & 4095) + wr * 64 + mi * 16 + g * 4;
          uint2 pv;
          pv.x = (uint32_t)f2bf(acc[mi][nj][0]) |
                 ((uint32_t)f2bf(acc[mi][nj][1]) << 16);
          pv.y = (uint32_t)f2bf(acc[mi][nj][2]) |
                 ((uint32_t)f2bf(acc[mi][nj][3]) << 16);
          *(uint2*)(Vg + ((size_t)(b * Hc + h) * HDc + hd) * Nc + nb) = pv;
        } else {
          uint16_t* dst = (part == 0) ? Qb : Kb;
          const size_t base = ((size_t)(b * Hc + h) * Nc) * HDc + hd;
#pragma unroll
          for (int rg = 0; rg < 4; ++rg) {
            const int m = m0 + wr * 64 + mi * 16 + g * 4 + rg;
            const int n = m & (Nc - 1);
            const float val = acc[mi][nj][rg];
            const float partner = __shfl_xor(val, 1);
            const float x2 = (e & 1) ? partner : -partner;
            const float2 cs =
                *(const float2*)(rot + ((size_t)(b * Nc + n) * Dc + d) * 2);
            dst[base + (size_t)n * HDc] = f2bf((val * cs.x + x2 * cs.y) * sc);
          }
        }
      }
    }
  } else {
#pragma unroll
    for (int nj = 0; nj < 4; ++nj) {
      const int e = n0 + wc * 64 + nj * 16 + l15;
      const float bia = bias[e];
#pragma unroll
      for (int mi = 0; mi < 4; ++mi)
#pragma unroll
        for (int rg = 0; rg < 4; ++rg) {
          const int m = m0 + wr * 64 + mi * 16 + g * 4 + rg;
          Out[(size_t)m * Dc + e] = acc[mi][nj][rg] + bia;
        }
    }
  }
}

// ---------------------------------------------------------------------------
// Flash attention, swapped-QK + swapped-PV, exp2-domain softmax (raw
// v_exp_f32), m-subtraction folded into the QK^T accumulator C-init
// (St starts at -mrow, so exp needs no v_sub), runtime double-buffer,
// chunk-XOR swizzled P tile, defer-rescale (T13), setprio (T5),
// ones-MFMA softmax denominator. launch_bounds(256,3): r7's (256,4)
// spilled ~32MB scratch (VGPR cap 128 too tight for O+St+qf+vb).
// ---------------------------------------------------------------------------
__global__ __launch_bounds__(256, 3) void attn_fa(
    const uint16_t* __restrict__ Qb, const uint16_t* __restrict__ Kb,
    const uint16_t* __restrict__ Vg, uint16_t* __restrict__ Ob) {
  __shared__ __align__(16) uint16_t Ks[2][64 * 64];  // [kv][d], chunk-swizzled
  __shared__ __align__(16) uint16_t Vt[2][64 * 64];  // [d][kv], chunk-swizzled
  __shared__ __align__(16) uint16_t Pl[4][16 * 64];  // per-wave P [q][kv], swz
  const int tid = threadIdx.x;
  const int lane = tid & 63, wave = tid >> 6;
  const int l15 = lane & 15, g = lane >> 4;
  const int swz = l15 & 7;
  const int bh = blockIdx.y;
  const int q0 = blockIdx.x * 128;
  const size_t bhN = (size_t)bh * Nc;
  const size_t bhHD = (size_t)bh * HDc;
  char* plw = (char*)&Pl[wave][0] + l15 * 128;  // this lane's q-row base

  // Q fragments register-resident for the whole block (B-operand layout)
  bf16x8 qf[2][2];
#pragma unroll
  for (int rf = 0; rf < 2; ++rf)
#pragma unroll
    for (int kk = 0; kk < 2; ++kk)
      qf[rf][kk] = *(const bf16x8*)(Qb + (bhN + q0 + wave * 32 + rf * 16 + l15) * HDc +
                                    kk * 32 + g * 8);

  // all-ones A-fragment for the denominator MFMA
  bf16x8 onef;
#pragma unroll
  for (int j = 0; j < 8; ++j) onef[j] = (__bf16)1.0f;

  const f32x4 fz = {0.f, 0.f, 0.f, 0.f};
  f32x4 O[2][4];
  // mrow starts at 0 (not -inf): S' is O(5) in log2 units, exp2(S') bounded;
  // the >11.5 rescale path keeps everything in range thereafter.
  float mrow[2] = {0.f, 0.f}, lrow[2] = {0.f, 0.f};
#pragma unroll
  for (int rf = 0; rf < 2; ++rf)
#pragma unroll
    for (int df = 0; df < 4; ++df) O[rf][df] = fz;

  // stage K/V tile t into given LDS buffers (linear dest, pre-swz source)
  auto stage = [&](uint16_t* ksd, uint16_t* vtd, int t) {
    const int kv0 = t * 64;
#pragma unroll
    for (int i = 0; i < 2; ++i) {
      const int ch = tid + i * 256;  // 0..511 : 64 rows x 8 chunks(16B)
      const int r = ch >> 3, c = ch & 7;
      const int cs = c ^ (r & 7);
      gload16(Kb + (bhN + kv0 + r) * HDc + cs * 8, ksd + ch * 8);
      gload16(Vg + (bhHD + r) * Nc + kv0 + cs * 8, vtd + ch * 8);
    }
  };

  stage(Ks[0], Vt[0], 0);
  int cur = 0;
  for (int t = 0; t < Nc / 64; ++t) {
    __syncthreads();  // drains vmcnt: tile t visible; prev iter's reads closed
    if (t < Nc / 64 - 1) stage(Ks[cur ^ 1], Vt[cur ^ 1], t + 1);

    const uint16_t* ks = &Ks[cur][0];
    const uint16_t* vt = &Vt[cur][0];

    // St[rf][cf]: lane(g,l15) reg r4 = S'[q=l15+rf*16][kv=cf*16+g*4+r4] - mrow
    // (subtraction folded into MFMA C-init)
    f32x4 St[2][4];
#pragma unroll
    for (int rf = 0; rf < 2; ++rf) {
      const f32x4 mi = {-mrow[rf], -mrow[rf], -mrow[rf], -mrow[rf]};
#pragma unroll
      for (int cf = 0; cf < 4; ++cf) St[rf][cf] = mi;
    }
    __builtin_amdgcn_s_setprio(1);
#pragma unroll
    for (int cf = 0; cf < 4; ++cf)
#pragma unroll
      for (int kk = 0; kk < 2; ++kk) {
        bf16x8 kf = *(const bf16x8*)(&ks[(cf * 16 + l15) * 64 + ((kk * 4 + g) ^ swz) * 8]);
        St[0][cf] = MFMA16(kf, qf[0][kk], St[0][cf]);
        St[1][cf] = MFMA16(kf, qf[1][kk], St[1][cf]);
      }
    __builtin_amdgcn_s_setprio(0);

    // V fragments (A-operand: row = d = df*16+l15)
    bf16x8 vb[4][2];
#pragma unroll
    for (int df = 0; df < 4; ++df) {
      vb[df][0] = *(const bf16x8*)(&vt[(df * 16 + l15) * 64 + (g ^ swz) * 8]);
      vb[df][1] = *(const bf16x8*)(&vt[(df * 16 + l15) * 64 + ((4 + g) ^ swz) * 8]);
    }

#pragma unroll
    for (int rf = 0; rf < 2; ++rf) {
      // tile max of (S - m_old): tree then combine 4 g-groups
      f32x4 m01, m23;
#pragma unroll
      for (int j = 0; j < 4; ++j) {
        m01[j] = fmaxf(St[rf][0][j], St[rf][1][j]);
        m23[j] = fmaxf(St[rf][2][j], St[rf][3][j]);
      }
      float pm = fmaxf(fmaxf(fmaxf(m01[0], m01[1]), fmaxf(m01[2], m01[3])),
                       fmaxf(fmaxf(m23[0], m23[1]), fmaxf(m23[2], m23[3])));
      pm = fmaxf(pm, __shfl_xor(pm, 16));
      pm = fmaxf(pm, __shfl_xor(pm, 32));

      // defer-rescale: only when max grew by > 11.5 (log2 units)
      if (__any(pm > 11.5f)) {
        const float d = fmaxf(pm, 0.f);  // per-row growth; 0 for shrunk rows
        mrow[rf] += d;
        const float corr = fexp2(-d);
        lrow[rf] *= corr;
#pragma unroll
        for (int df = 0; df < 4; ++df)
#pragma unroll
          for (int r4 = 0; r4 < 4; ++r4) O[rf][df][r4] *= corr;
#pragma unroll
        for (int cf = 0; cf < 4; ++cf)
#pragma unroll
          for (int r4 = 0; r4 < 4; ++r4) St[rf][cf][r4] -= d;
      }

#pragma unroll
      for (int cf = 0; cf < 4; ++cf)
#pragma unroll
        for (int r4 = 0; r4 < 4; ++r4) St[rf][cf][r4] = fexp2(St[rf][cf][r4]);

      // P pack into chunk-XOR swizzled [q][kv] tile: elem (q,kv) at byte
      // q*128 + ((kv>>3)^(q&7))*16 + (kv&7)*2. Lane writes kv=cf*16+g*4+r4.
#pragma unroll
      for (int cf = 0; cf < 4; ++cf) {
        uint2 pv;
        pv.x = (uint32_t)f2bf(St[rf][cf][0]) | ((uint32_t)f2bf(St[rf][cf][1]) << 16);
        pv.y = (uint32_t)f2bf(St[rf][cf][2]) | ((uint32_t)f2bf(St[rf][cf][3]) << 16);
        *(uint2*)(plw + (((cf * 2 + (g >> 1)) ^ swz) * 16) + (g & 1) * 8) = pv;
      }

      // P fragments (B-operand: col = q = l15, 8 contiguous kv per lane)
      bf16x8 pa0 = *(const bf16x8*)(plw + ((g ^ swz) * 16));
      bf16x8 pa1 = *(const bf16x8*)(plw + (((4 + g) ^ swz) * 16));

      // denominator via ones-MFMA: sums ALL 64 kv (cross-g) in-pipe, in-lane
      f32x4 ls = fz;
      __builtin_amdgcn_s_setprio(1);
      ls = MFMA16(onef, pa0, ls);
      ls = MFMA16(onef, pa1, ls);
      // PV with swapped args: Ot[col=q=l15][row=d] = mfma(V-frag, P-frag)
#pragma unroll
      for (int df = 0; df < 4; ++df) {
        O[rf][df] = MFMA16(vb[df][0], pa0, O[rf][df]);
        O[rf][df] = MFMA16(vb[df][1], pa1, O[rf][df]);
      }
      __builtin_amdgcn_s_setprio(0);
      lrow[rf] += ls[0];
    }
    cur ^= 1;
  }

  // epilogue: per-lane normalize (q = l15), packed 8B stores
  const int b = bh >> 4, h = bh & 15;
#pragma unroll
  for (int rf = 0; rf < 2; ++rf) {
    const float inv = 1.f / lrow[rf];
    const int n = q0 + wave * 32 + rf * 16 + l15;
    uint16_t* orow = Ob + ((size_t)b * Nc + n) * Dc + h * HDc;
#pragma unroll
    for (int df = 0; df < 4; ++df) {
      uint2 pv;
      pv.x = (uint32_t)f2bf(O[rf][df][0] * inv) |
             ((uint32_t)f2bf(O[rf][df][1] * inv) << 16);
      pv.y = (uint32_t)f2bf(O[rf][df][2] * inv) |
             ((uint32_t)f2bf(O[rf][df][3] * inv) << 16);
      *(uint2*)(orow + df * 16 + g * 4) = pv;
    }
  }
}

extern "C" void kernel_launch(void* const* d_in, const int* in_sizes, int n_in,
                              void* d_out, int out_size, void* d_ws, size_t ws_size,
                              hipStream_t stream) {
  const float* x = (const float*)d_in[0];      // [B,N,D] f32
  const float* rot = (const float*)d_in[1];    // [B,N,D,2] f32
  const float* Wqkv = (const float*)d_in[2];   // [3D,D] f32
  const float* Wout = (const float*)d_in[3];   // [D,D] f32
  const float* bout = (const float*)d_in[4];   // [D] f32
  float* out = (float*)d_out;                  // [B,N,D] f32

  uint16_t* ws = (uint16_t*)d_ws;
  const size_t XSZ = (size_t)Bc * Nc * Dc;        // 16,777,216 elems
  const size_t W1SZ = (size_t)3 * Dc * Dc;        //  3,145,728
  const size_t W2SZ = (size_t)Dc * Dc;            //  1,048,576
  uint16_t* xb = ws;               // bf16 x; ALIASED with At (safe: xb's last
  uint16_t* At = ws;               // read is gemm1; At first written by attn)
  uint16_t* Qb = ws + XSZ;
  uint16_t* Kb = ws + 2 * XSZ;
  uint16_t* Vg = ws + 3 * XSZ;     // transposed [B,H,HD,N]
  uint16_t* Wqb = ws + 4 * XSZ;
  uint16_t* Wob = ws + 4 * XSZ + W1SZ;
  // total: 4*XSZ + W1SZ + W2SZ = 71,303,168 elems = 142.6 MB

  dim3 blk(256);
  cvt_f32_bf16<<<dim3((XSZ / 8 + 255) / 256), blk, 0, stream>>>(x, xb, (int)XSZ);
  cvt_f32_bf16<<<dim3((W1SZ / 8 + 255) / 256), blk, 0, stream>>>(Wqkv, Wqb, (int)W1SZ);
  cvt_f32_bf16<<<dim3((W2SZ / 8 + 255) / 256), blk, 0, stream>>>(Wout, Wob, (int)W2SZ);

  gemm_bt<0><<<dim3((3 * Dc) / 128, (Bc * Nc) / 128), blk, 0, stream>>>(
      xb, Wqb, Dc, rot, Qb, Kb, Vg, nullptr, nullptr);
  attn_fa<<<dim3(Nc / 128, Bc * Hc), blk, 0, stream>>>(Qb, Kb, Vg, At);
  gemm_bt<1><<<dim3(Dc / 128, (Bc * Nc) / 128), blk, 0, stream>>>(
      At, Wob, Dc, nullptr, nullptr, nullptr, nullptr, bout, out);
}

// Round 9
// 637.134 us; speedup vs baseline: 1.9085x; 1.0352x over previous
//
#include <hip/hip_runtime.h>
#include <hip/hip_bf16.h>
#include <stdint.h>
#include <stddef.h>

typedef __attribute__((ext_vector_type(8))) __bf16 bf16x8;
typedef __attribute__((ext_vector_type(4))) __bf16 bf16x4;
typedef __attribute__((ext_vector_type(4))) float f32x4;
typedef __attribute__((ext_vector_type(16))) float f32x16;

#define MFMA16(a, b, c) __builtin_amdgcn_mfma_f32_16x16x32_bf16((a), (b), (c), 0, 0, 0)
#define MFMA32(a, b, c) __builtin_amdgcn_mfma_f32_32x32x16_bf16((a), (b), (c), 0, 0, 0)

static constexpr int Bc = 4, Nc = 4096, Dc = 1024, Hc = 16, HDc = 64;

__device__ __forceinline__ uint16_t f2bf(float f) {
  __bf16 h = (__bf16)f;
  return __builtin_bit_cast(uint16_t, h);
}

// raw v_exp_f32 (no libm edge-case code; inputs here are finite, bounded)
__device__ __forceinline__ float fexp2(float x) {
#if __has_builtin(__builtin_amdgcn_exp2f)
  return __builtin_amdgcn_exp2f(x);
#else
  return __builtin_exp2f(x);
#endif
}

// async global->LDS, 16B per lane. LDS dest must be wave-uniform base + lane*16.
__device__ __forceinline__ void gload16(const void* g, void* l) {
  __builtin_amdgcn_global_load_lds(
      (__attribute__((address_space(1))) void*)(g),
      (__attribute__((address_space(3))) void*)(l), 16, 0, 0);
}

// ---------------------------------------------------------------------------
// f32 -> bf16 convert (vectorized, 8 elems/thread). n must be a multiple of 8.
// ---------------------------------------------------------------------------
__global__ __launch_bounds__(256) void cvt_f32_bf16(
    const float* __restrict__ src, uint16_t* __restrict__ dst, int n) {
  const int i = (blockIdx.x * 256 + threadIdx.x) * 8;
  if (i >= n) return;
  const float4 a = *(const float4*)(src + i);
  const float4 b = *(const float4*)(src + i + 4);
  union { uint16_t u[8]; uint4 v; } o;
  o.u[0] = f2bf(a.x); o.u[1] = f2bf(a.y); o.u[2] = f2bf(a.z); o.u[3] = f2bf(a.w);
  o.u[4] = f2bf(b.x); o.u[5] = f2bf(b.y); o.u[6] = f2bf(b.z); o.u[7] = f2bf(b.w);
  *(uint4*)(dst + i) = o.v;
}

// ---------------------------------------------------------------------------
// BT-GEMM: C[m, e] = sum_k A[m, k] * Bw[e, k].  128x128 tile, BK=64, 4 waves.
// EPI=0: QKV projection epilogue -> RoPE (f32 rot) -> Q/K [B,H,N,HD] bf16,
//        Q pre-scaled by 0.125*log2(e) (exp2-domain softmax),
//        V transposed [B,H,HD,N] bf16
// EPI=1: bias add (f32) -> Out [M, 1024] f32
// ---------------------------------------------------------------------------
template <int EPI>
__global__ __launch_bounds__(256, 2) void gemm_bt(
    const uint16_t* __restrict__ A, const uint16_t* __restrict__ Bw, int K,
    const float* __restrict__ rot, uint16_t* __restrict__ Qb,
    uint16_t* __restrict__ Kb, uint16_t* __restrict__ Vg,
    const float* __restrict__ bias, float* __restrict__ Out) {
  __shared__ __align__(16) uint16_t As[128 * 64];
  __shared__ __align__(16) uint16_t Bs[128 * 64];
  const int tid = threadIdx.x;
  const int lane = tid & 63, wave = tid >> 6;
  const int l15 = lane & 15, g = lane >> 4;
  const int wr = wave >> 1, wc = wave & 1;
  const int m0 = blockIdx.y * 128;
  const int n0 = blockIdx.x * 128;

  f32x4 acc[4][4];
  const f32x4 fz = {0.f, 0.f, 0.f, 0.f};
#pragma unroll
  for (int i = 0; i < 4; ++i)
#pragma unroll
    for (int j = 0; j < 4; ++j) acc[i][j] = fz;

  for (int kt = 0; kt < K; kt += 64) {
    __syncthreads();  // previous iter's LDS reads done before overwrite
#pragma unroll
    for (int i = 0; i < 4; ++i) {
      const int chunk = tid + i * 256;  // 0..1023 : 128 rows x 8 chunks(16B)
      const int r = chunk >> 3, c = chunk & 7;
      const int cs = c ^ (r & 7);  // pre-swizzled source (linear LDS dest)
      gload16(A + (size_t)(m0 + r) * K + kt + cs * 8, &As[chunk * 8]);
      gload16(Bw + (size_t)(n0 + r) * K + kt + cs * 8, &Bs[chunk * 8]);
    }
    __syncthreads();  // implies vmcnt(0): staged data visible

    bf16x8 af[4][2], bfr[4][2];
#pragma unroll
    for (int mi = 0; mi < 4; ++mi)
#pragma unroll
      for (int kk = 0; kk < 2; ++kk) {
        const int r = wr * 64 + mi * 16 + l15;
        const int ca = (kk * 4 + g) ^ (r & 7);
        af[mi][kk] = *(const bf16x8*)((const char*)As + r * 128 + ca * 16);
        const int r2 = wc * 64 + mi * 16 + l15;
        const int cb = (kk * 4 + g) ^ (r2 & 7);
        bfr[mi][kk] = *(const bf16x8*)((const char*)Bs + r2 * 128 + cb * 16);
      }
#pragma unroll
    for (int mi = 0; mi < 4; ++mi)
#pragma unroll
      for (int nj = 0; nj < 4; ++nj)
#pragma unroll
        for (int kk = 0; kk < 2; ++kk)
          acc[mi][nj] = MFMA16(af[mi][kk], bfr[nj][kk], acc[mi][nj]);
  }

  if (EPI == 0) {
    // C rows m -> (b, n); cols e -> (part, h, hd). RoPE pair is lane^1.
    const int b = m0 >> 12;  // 4096 rows per batch, 128 | 4096 -> uniform
#pragma unroll
    for (int nj = 0; nj < 4; ++nj) {
      const int e = n0 + wc * 64 + nj * 16 + l15;
      const int part = e >> 10;           // wave-uniform (16-col tile)
      const int d = e & 1023;
      const int h = d >> 6, hd = d & 63;
      // exp2-domain: fold 0.125*log2(e) into Q
      const float sc = (part == 0) ? 0.18033688011112042f : 1.0f;
#pragma unroll
      for (int mi = 0; mi < 4; ++mi) {
        if (part == 2) {
          // V transposed: [B, H, HD, N]; pack 4 consecutive n into 8B store
          const int nb = (m0 & 4095) + wr * 64 + mi * 16 + g * 4;
          uint2 pv;
          pv.x = (uint32_t)f2bf(acc[mi][nj][0]) |
                 ((uint32_t)f2bf(acc[mi][nj][1]) << 16);
          pv.y = (uint32_t)f2bf(acc[mi][nj][2]) |
                 ((uint32_t)f2bf(acc[mi][nj][3]) << 16);
          *(uint2*)(Vg + ((size_t)(b * Hc + h) * HDc + hd) * Nc + nb) = pv;
        } else {
          uint16_t* dst = (part == 0) ? Qb : Kb;
          const size_t base = ((size_t)(b * Hc + h) * Nc) * HDc + hd;
#pragma unroll
          for (int rg = 0; rg < 4; ++rg) {
            const int m = m0 + wr * 64 + mi * 16 + g * 4 + rg;
            const int n = m & (Nc - 1);
            const float val = acc[mi][nj][rg];
            const float partner = __shfl_xor(val, 1);
            const float x2 = (e & 1) ? partner : -partner;
            const float2 cs =
                *(const float2*)(rot + ((size_t)(b * Nc + n) * Dc + d) * 2);
            dst[base + (size_t)n * HDc] = f2bf((val * cs.x + x2 * cs.y) * sc);
          }
        }
      }
    }
  } else {
#pragma unroll
    for (int nj = 0; nj < 4; ++nj) {
      const int e = n0 + wc * 64 + nj * 16 + l15;
      const float bia = bias[e];
#pragma unroll
      for (int mi = 0; mi < 4; ++mi)
#pragma unroll
        for (int rg = 0; rg < 4; ++rg) {
          const int m = m0 + wr * 64 + mi * 16 + g * 4 + rg;
          Out[(size_t)m * Dc + e] = acc[mi][nj][rg] + bia;
        }
    }
  }
}

// ---------------------------------------------------------------------------
// Flash attention, 32x32x16 MFMA variant.
//  QK^T swapped: St[c] = mfma32(K-frag, Q-frag): col=q=lane&31, so each lane
//  holds 32 S-values (2 kv-tiles x 16 regs) of ONE q row; partner lane^32
//  holds the interleaved other kv half. Softmax fully in-lane (31 fmax +
//  1 bpermute). P stays IN REGISTERS: the PV kv-axis is permuted identically
//  on both operands (P B-frag = direct St reg renaming; V A-frag = two
//  ds_read_b64 4-runs), so no P LDS round-trip at all. LDS = 32KB (K/V dbuf).
//  C-init = -mrow fold, raw exp2, defer-rescale (T13), ones-MFMA denominator,
//  setprio (T5), dbuf staging via global_load_lds.
// ---------------------------------------------------------------------------
__global__ __launch_bounds__(256, 3) void attn_fa(
    const uint16_t* __restrict__ Qb, const uint16_t* __restrict__ Kb,
    const uint16_t* __restrict__ Vg, uint16_t* __restrict__ Ob) {
  __shared__ __align__(16) uint16_t Ks[2][64 * 64];  // [kv][d], chunk-swizzled
  __shared__ __align__(16) uint16_t Vt[2][64 * 64];  // [d][kv], chunk-swizzled
  const int tid = threadIdx.x;
  const int lane = tid & 63, wave = tid >> 6;
  const int l31 = lane & 31, hi = lane >> 5;
  const int sw = l31 & 7;  // swizzle index (row&7 for all row sets used)
  const int bh = blockIdx.y;
  const int q0 = blockIdx.x * 128;
  const size_t bhN = (size_t)bh * Nc;
  const size_t bhHD = (size_t)bh * HDc;

  // Q B-fragments (col = q = l31, k(d) = ks*16 + hi*8 + j), register-resident
  bf16x8 qf[4];
#pragma unroll
  for (int ks = 0; ks < 4; ++ks)
    qf[ks] = *(const bf16x8*)(Qb + (bhN + q0 + wave * 32 + l31) * HDc +
                              ks * 16 + hi * 8);

  // all-ones A-fragment for the denominator MFMA
  bf16x8 onef;
#pragma unroll
  for (int j = 0; j < 8; ++j) onef[j] = (__bf16)1.0f;

  f32x16 O16[2] = {{}, {}};
  float mrow = 0.f, lrow = 0.f;  // defer-max: start at 0, rescale on >11.5

  // stage K/V tile t into given LDS buffers (linear dest, pre-swz source)
  auto stage = [&](uint16_t* ksd, uint16_t* vtd, int t) {
    const int kv0 = t * 64;
#pragma unroll
    for (int i = 0; i < 2; ++i) {
      const int ch = tid + i * 256;  // 0..511 : 64 rows x 8 chunks(16B)
      const int r = ch >> 3, c = ch & 7;
      const int cs = c ^ (r & 7);
      gload16(Kb + (bhN + kv0 + r) * HDc + cs * 8, ksd + ch * 8);
      gload16(Vg + (bhHD + r) * Nc + kv0 + cs * 8, vtd + ch * 8);
    }
  };

  stage(Ks[0], Vt[0], 0);
  int cur = 0;
  for (int t = 0; t < Nc / 64; ++t) {
    __syncthreads();  // drains vmcnt: tile t visible; prev iter's reads closed
    if (t < Nc / 64 - 1) stage(Ks[cur ^ 1], Vt[cur ^ 1], t + 1);

    const uint16_t* ksp = &Ks[cur][0];
    const uint16_t* vtp = &Vt[cur][0];

    // QK^T: St[c] reg r = S'[kv = c*32 + (r&3) + 8*(r>>2) + 4*hi][q=l31] - mrow
    f32x16 St[2];
#pragma unroll
    for (int r = 0; r < 16; ++r) { St[0][r] = -mrow; St[1][r] = -mrow; }
    __builtin_amdgcn_s_setprio(1);
#pragma unroll
    for (int c = 0; c < 2; ++c)
#pragma unroll
      for (int ks = 0; ks < 4; ++ks) {
        bf16x8 kf = *(const bf16x8*)(&ksp[(c * 32 + l31) * 64 +
                                          (((ks * 2 + hi) ^ sw) * 8)]);
        St[c] = MFMA32(kf, qf[ks], St[c]);
      }
    __builtin_amdgcn_s_setprio(0);

    // in-lane max over 32, then combine with partner lane (^32)
    f32x16 mm;
#pragma unroll
    for (int r = 0; r < 16; ++r) mm[r] = fmaxf(St[0][r], St[1][r]);
    float m8[8];
#pragma unroll
    for (int r = 0; r < 8; ++r) m8[r] = fmaxf(mm[r], mm[r + 8]);
    float pm = fmaxf(fmaxf(fmaxf(m8[0], m8[1]), fmaxf(m8[2], m8[3])),
                     fmaxf(fmaxf(m8[4], m8[5]), fmaxf(m8[6], m8[7])));
    pm = fmaxf(pm, __shfl_xor(pm, 32));

    // defer-rescale: only when max grew by > 11.5 (log2 units)
    if (__any(pm > 11.5f)) {
      const float dd = fmaxf(pm, 0.f);
      mrow += dd;
      const float corr = fexp2(-dd);
      lrow *= corr;
      O16[0] *= corr;
      O16[1] *= corr;
      St[0] -= dd;
      St[1] -= dd;
    }

#pragma unroll
    for (int r = 0; r < 16; ++r) {
      St[0][r] = fexp2(St[0][r]);
      St[1][r] = fexp2(St[1][r]);
    }

    // P B-fragments: pure register renaming. Window w covers kv
    // [32*(w>>1)+16*(w&1), +16); lane's slot j maps to kv base1+j / base2+j
    // with base1 = 32c+16(w&1)+4hi, base2 = base1+8 — exactly St regs.
    bf16x8 pa[4];
#pragma unroll
    for (int w = 0; w < 4; ++w) {
      const int c = w >> 1, rr = (w & 1) * 2;
#pragma unroll
      for (int j = 0; j < 4; ++j) {
        pa[w][j] = (__bf16)St[c][rr * 4 + j];
        pa[w][j + 4] = (__bf16)St[c][rr * 4 + 4 + j];
      }
    }

    // denominator: ones-MFMA sums all 64 kv (any permutation), in-lane col=q
    f32x16 ls = {};
    __builtin_amdgcn_s_setprio(1);
#pragma unroll
    for (int w = 0; w < 4; ++w) ls = MFMA32(onef, pa[w], ls);

    // PV: O16[df] += mfma32(V-frag, pa[w]); V-frag = two 4-run b64 reads
    // matching pa's kv permutation (base1, base2 runs).
#pragma unroll
    for (int df = 0; df < 2; ++df) {
      const int drow = df * 32 + l31;
#pragma unroll
      for (int w = 0; w < 4; ++w) {
        const int cc = (w >> 1) * 4 + (w & 1) * 2;
        bf16x4 vlo = *(const bf16x4*)(&vtp[drow * 64 + ((cc ^ sw) * 8) + hi * 4]);
        bf16x4 vhi = *(const bf16x4*)(&vtp[drow * 64 + (((cc + 1) ^ sw) * 8) + hi * 4]);
        bf16x8 vf;
#pragma unroll
        for (int j = 0; j < 4; ++j) { vf[j] = vlo[j]; vf[j + 4] = vhi[j]; }
        O16[df] = MFMA32(vf, pa[w], O16[df]);
      }
    }
    __builtin_amdgcn_s_setprio(0);
    lrow += ls[0];
    cur ^= 1;
  }

  // epilogue: per-lane normalize (q = l31), packed 8B stores.
  // O16[df] reg r -> d = df*32 + (r&3) + 8*(r>>2) + 4*hi.
  const int b = bh >> 4, h = bh & 15;
  const float inv = 1.f / lrow;
  const int n = q0 + wave * 32 + l31;
  uint16_t* orow = Ob + ((size_t)b * Nc + n) * Dc + h * HDc;
#pragma unroll
  for (int df = 0; df < 2; ++df)
#pragma unroll
    for (int r2 = 0; r2 < 4; ++r2) {
      uint2 pv;
      pv.x = (uint32_t)f2bf(O16[df][r2 * 4 + 0] * inv) |
             ((uint32_t)f2bf(O16[df][r2 * 4 + 1] * inv) << 16);
      pv.y = (uint32_t)f2bf(O16[df][r2 * 4 + 2] * inv) |
             ((uint32_t)f2bf(O16[df][r2 * 4 + 3] * inv) << 16);
      *(uint2*)(orow + df * 32 + r2 * 8 + hi * 4) = pv;
    }
}

extern "C" void kernel_launch(void* const* d_in, const int* in_sizes, int n_in,
                              void* d_out, int out_size, void* d_ws, size_t ws_size,
                              hipStream_t stream) {
  const float* x = (const float*)d_in[0];      // [B,N,D] f32
  const float* rot = (const float*)d_in[1];    // [B,N,D,2] f32
  const float* Wqkv = (const float*)d_in[2];   // [3D,D] f32
  const float* Wout = (const float*)d_in[3];   // [D,D] f32
  const float* bout = (const float*)d_in[4];   // [D] f32
  float* out = (float*)d_out;                  // [B,N,D] f32

  uint16_t* ws = (uint16_t*)d_ws;
  const size_t XSZ = (size_t)Bc * Nc * Dc;        // 16,777,216 elems
  const size_t W1SZ = (size_t)3 * Dc * Dc;        //  3,145,728
  const size_t W2SZ = (size_t)Dc * Dc;            //  1,048,576
  uint16_t* xb = ws;               // bf16 x; ALIASED with At (safe: xb's last
  uint16_t* At = ws;               // read is gemm1; At first written by attn)
  uint16_t* Qb = ws + XSZ;
  uint16_t* Kb = ws + 2 * XSZ;
  uint16_t* Vg = ws + 3 * XSZ;     // transposed [B,H,HD,N]
  uint16_t* Wqb = ws + 4 * XSZ;
  uint16_t* Wob = ws + 4 * XSZ + W1SZ;
  // total: 4*XSZ + W1SZ + W2SZ = 71,303,168 elems = 142.6 MB

  dim3 blk(256);
  cvt_f32_bf16<<<dim3((XSZ / 8 + 255) / 256), blk, 0, stream>>>(x, xb, (int)XSZ);
  cvt_f32_bf16<<<dim3((W1SZ / 8 + 255) / 256), blk, 0, stream>>>(Wqkv, Wqb, (int)W1SZ);
  cvt_f32_bf16<<<dim3((W2SZ / 8 + 255) / 256), blk, 0, stream>>>(Wout, Wob, (int)W2SZ);

  gemm_bt<0><<<dim3((3 * Dc) / 128, (Bc * Nc) / 128), blk, 0, stream>>>(
      xb, Wqb, Dc, rot, Qb, Kb, Vg, nullptr, nullptr);
  attn_fa<<<dim3(Nc / 128, Bc * Hc), blk, 0, stream>>>(Qb, Kb, Vg, At);
  gemm_bt<1><<<dim3(Dc / 128, (Bc * Nc) / 128), blk, 0, stream>>>(
      At, Wob, Dc, nullptr, nullptr, nullptr, nullptr, bout, out);
}

// Round 10
// 599.376 us; speedup vs baseline: 2.0287x; 1.0630x over previous
//
#include <hip/hip_runtime.h>
#include <hip/hip_bf16.h>
#include <stdint.h>
#include <stddef.h>

typedef __attribute__((ext_vector_type(8))) __bf16 bf16x8;
typedef __attribute__((ext_vector_type(4))) float f32x4;
typedef __attribute__((ext_vector_type(16))) float f32x16;

#define MFMA16(a, b, c) __builtin_amdgcn_mfma_f32_16x16x32_bf16((a), (b), (c), 0, 0, 0)
#define MFMA32(a, b, c) __builtin_amdgcn_mfma_f32_32x32x16_bf16((a), (b), (c), 0, 0, 0)

static constexpr int Bc = 4, Nc = 4096, Dc = 1024, Hc = 16, HDc = 64;

__device__ __forceinline__ uint16_t f2bf(float f) {
  __bf16 h = (__bf16)f;
  return __builtin_bit_cast(uint16_t, h);
}

// raw v_exp_f32 (no libm edge-case code; inputs here are finite, bounded)
__device__ __forceinline__ float fexp2(float x) {
#if __has_builtin(__builtin_amdgcn_exp2f)
  return __builtin_amdgcn_exp2f(x);
#else
  return __builtin_exp2f(x);
#endif
}

// async global->LDS, 16B per lane. LDS dest must be wave-uniform base + lane*16.
__device__ __forceinline__ void gload16(const void* g, void* l) {
  __builtin_amdgcn_global_load_lds(
      (__attribute__((address_space(1))) void*)(g),
      (__attribute__((address_space(3))) void*)(l), 16, 0, 0);
}

// ---------------------------------------------------------------------------
// f32 -> bf16 convert (vectorized, 8 elems/thread). n must be a multiple of 8.
// ---------------------------------------------------------------------------
__global__ __launch_bounds__(256) void cvt_f32_bf16(
    const float* __restrict__ src, uint16_t* __restrict__ dst, int n) {
  const int i = (blockIdx.x * 256 + threadIdx.x) * 8;
  if (i >= n) return;
  const float4 a = *(const float4*)(src + i);
  const float4 b = *(const float4*)(src + i + 4);
  union { uint16_t u[8]; uint4 v; } o;
  o.u[0] = f2bf(a.x); o.u[1] = f2bf(a.y); o.u[2] = f2bf(a.z); o.u[3] = f2bf(a.w);
  o.u[4] = f2bf(b.x); o.u[5] = f2bf(b.y); o.u[6] = f2bf(b.z); o.u[7] = f2bf(b.w);
  *(uint4*)(dst + i) = o.v;
}

// ---------------------------------------------------------------------------
// BT-GEMM: C[m, e] = sum_k A[m, k] * Bw[e, k].  128x128 tile, BK=64, 4 waves.
// EPI=0: QKV projection epilogue -> RoPE (f32 rot) -> Q/K [B,H,N,HD] bf16,
//        Q pre-scaled by 0.125*log2(e) (exp2-domain softmax),
//        V transposed [B,H,HD,N] bf16
// EPI=1: bias add (f32) -> Out [M, 1024] f32
// ---------------------------------------------------------------------------
template <int EPI>
__global__ __launch_bounds__(256, 2) void gemm_bt(
    const uint16_t* __restrict__ A, const uint16_t* __restrict__ Bw, int K,
    const float* __restrict__ rot, uint16_t* __restrict__ Qb,
    uint16_t* __restrict__ Kb, uint16_t* __restrict__ Vg,
    const float* __restrict__ bias, float* __restrict__ Out) {
  __shared__ __align__(16) uint16_t As[128 * 64];
  __shared__ __align__(16) uint16_t Bs[128 * 64];
  const int tid = threadIdx.x;
  const int lane = tid & 63, wave = tid >> 6;
  const int l15 = lane & 15, g = lane >> 4;
  const int wr = wave >> 1, wc = wave & 1;
  const int m0 = blockIdx.y * 128;
  const int n0 = blockIdx.x * 128;

  f32x4 acc[4][4];
  const f32x4 fz = {0.f, 0.f, 0.f, 0.f};
#pragma unroll
  for (int i = 0; i < 4; ++i)
#pragma unroll
    for (int j = 0; j < 4; ++j) acc[i][j] = fz;

  for (int kt = 0; kt < K; kt += 64) {
    __syncthreads();  // previous iter's LDS reads done before overwrite
#pragma unroll
    for (int i = 0; i < 4; ++i) {
      const int chunk = tid + i * 256;  // 0..1023 : 128 rows x 8 chunks(16B)
      const int r = chunk >> 3, c = chunk & 7;
      const int cs = c ^ (r & 7);  // pre-swizzled source (linear LDS dest)
      gload16(A + (size_t)(m0 + r) * K + kt + cs * 8, &As[chunk * 8]);
      gload16(Bw + (size_t)(n0 + r) * K + kt + cs * 8, &Bs[chunk * 8]);
    }
    __syncthreads();  // implies vmcnt(0): staged data visible

    bf16x8 af[4][2], bfr[4][2];
#pragma unroll
    for (int mi = 0; mi < 4; ++mi)
#pragma unroll
      for (int kk = 0; kk < 2; ++kk) {
        const int r = wr * 64 + mi * 16 + l15;
        const int ca = (kk * 4 + g) ^ (r & 7);
        af[mi][kk] = *(const bf16x8*)((const char*)As + r * 128 + ca * 16);
        const int r2 = wc * 64 + mi * 16 + l15;
        const int cb = (kk * 4 + g) ^ (r2 & 7);
        bfr[mi][kk] = *(const bf16x8*)((const char*)Bs + r2 * 128 + cb * 16);
      }
#pragma unroll
    for (int mi = 0; mi < 4; ++mi)
#pragma unroll
      for (int nj = 0; nj < 4; ++nj)
#pragma unroll
        for (int kk = 0; kk < 2; ++kk)
          acc[mi][nj] = MFMA16(af[mi][kk], bfr[nj][kk], acc[mi][nj]);
  }

  if (EPI == 0) {
    // C rows m -> (b, n); cols e -> (part, h, hd). RoPE pair is lane^1.
    const int b = m0 >> 12;  // 4096 rows per batch, 128 | 4096 -> uniform
#pragma unroll
    for (int nj = 0; nj < 4; ++nj) {
      const int e = n0 + wc * 64 + nj * 16 + l15;
      const int part = e >> 10;           // wave-uniform (16-col tile)
      const int d = e & 1023;
      const int h = d >> 6, hd = d & 63;
      // exp2-domain: fold 0.125*log2(e) into Q
      const float sc = (part == 0) ? 0.18033688011112042f : 1.0f;
#pragma unroll
      for (int mi = 0; mi < 4; ++mi) {
        if (part == 2) {
          // V transposed: [B, H, HD, N]; pack 4 consecutive n into 8B store
          const int nb = (m0 & 4095) + wr * 64 + mi * 16 + g * 4;
          uint2 pv;
          pv.x = (uint32_t)f2bf(acc[mi][nj][0]) |
                 ((uint32_t)f2bf(acc[mi][nj][1]) << 16);
          pv.y = (uint32_t)f2bf(acc[mi][nj][2]) |
                 ((uint32_t)f2bf(acc[mi][nj][3]) << 16);
          *(uint2*)(Vg + ((size_t)(b * Hc + h) * HDc + hd) * Nc + nb) = pv;
        } else {
          uint16_t* dst = (part == 0) ? Qb : Kb;
          const size_t base = ((size_t)(b * Hc + h) * Nc) * HDc + hd;
#pragma unroll
          for (int rg = 0; rg < 4; ++rg) {
            const int m = m0 + wr * 64 + mi * 16 + g * 4 + rg;
            const int n = m & (Nc - 1);
            const float val = acc[mi][nj][rg];
            const float partner = __shfl_xor(val, 1);
            const float x2 = (e & 1) ? partner : -partner;
            const float2 cs =
                *(const float2*)(rot + ((size_t)(b * Nc + n) * Dc + d) * 2);
            dst[base + (size_t)n * HDc] = f2bf((val * cs.x + x2 * cs.y) * sc);
          }
        }
      }
    }
  } else {
#pragma unroll
    for (int nj = 0; nj < 4; ++nj) {
      const int e = n0 + wc * 64 + nj * 16 + l15;
      const float bia = bias[e];
#pragma unroll
      for (int mi = 0; mi < 4; ++mi)
#pragma unroll
        for (int rg = 0; rg < 4; ++rg) {
          const int m = m0 + wr * 64 + mi * 16 + g * 4 + rg;
          Out[(size_t)m * Dc + e] = acc[mi][nj][rg] + bia;
        }
    }
  }
}

// ---------------------------------------------------------------------------
// Flash attention, 32x32x16 MFMA, in-register P (r9) + INTERLEAVED V LDS
// layout (r10): V is reg-staged (global->reg->ds_write) storing each 16-kv
// window as [pos=(kv&3)+4*((kv>>3)&1)][hiclass=(kv>>2)&1], so the PV
// A-fragment is ONE ds_read_b128 at chunk (2m+hi)^sw — same phase-uniform
// bank geometry as the K read (r9's 2xb64 gather was half-bank per phase ->
// 5e7 conflicts). K stays global_load_lds. Everything else as r9.
// ---------------------------------------------------------------------------
__global__ __launch_bounds__(256, 3) void attn_fa(
    const uint16_t* __restrict__ Qb, const uint16_t* __restrict__ Kb,
    const uint16_t* __restrict__ Vg, uint16_t* __restrict__ Ob) {
  __shared__ __align__(16) uint16_t Ks[2][64 * 64];  // [kv][d], chunk-swizzled
  __shared__ __align__(16) uint16_t Vt[2][64 * 64];  // [d][kv-interleaved]
  const int tid = threadIdx.x;
  const int lane = tid & 63, wave = tid >> 6;
  const int l31 = lane & 31, hi = lane >> 5;
  const int sw = l31 & 7;  // swizzle index (row&7 for all row sets used)
  const int bh = blockIdx.y;
  const int q0 = blockIdx.x * 128;
  const size_t bhN = (size_t)bh * Nc;
  const size_t bhHD = (size_t)bh * HDc;

  // Q B-fragments (col = q = l31, k(d) = ks*16 + hi*8 + j), register-resident
  bf16x8 qf[4];
#pragma unroll
  for (int ks = 0; ks < 4; ++ks)
    qf[ks] = *(const bf16x8*)(Qb + (bhN + q0 + wave * 32 + l31) * HDc +
                              ks * 16 + hi * 8);

  // all-ones A-fragment for the denominator MFMA
  bf16x8 onef;
#pragma unroll
  for (int j = 0; j < 8; ++j) onef[j] = (__bf16)1.0f;

  f32x16 O16[2] = {{}, {}};
  float mrow = 0.f, lrow = 0.f;  // defer-max: start at 0, rescale on >11.5

  // stage K (gload_lds, linear dest / pre-swz source) and V (reg-staged,
  // interleaved dest) for tile t.
  auto stage = [&](uint16_t* ksd, uint16_t* vtd, int t) {
    const int kv0 = t * 64;
#pragma unroll
    for (int i = 0; i < 2; ++i) {
      const int ch = tid + i * 256;  // 0..511 : 64 rows x 8 chunks(16B)
      const int r = ch >> 3, c = ch & 7;
      const int cs = c ^ (r & 7);
      gload16(Kb + (bhN + kv0 + r) * HDc + cs * 8, ksd + ch * 8);
      // V: global chunk c (kv c*8..c*8+7) -> LDS chunks (2*(c>>1)+{0,1})^(r&7),
      // 8B halves at byte offset 8*(c&1).
      const uint4 gv = *(const uint4*)(Vg + (bhHD + r) * Nc + kv0 + c * 8);
      const int cA = (2 * (c >> 1)) ^ (r & 7);
      const int cB = (2 * (c >> 1) + 1) ^ (r & 7);
      uint2 vA; vA.x = gv.x; vA.y = gv.y;
      uint2 vB; vB.x = gv.z; vB.y = gv.w;
      *(uint2*)(vtd + r * 64 + cA * 8 + (c & 1) * 4) = vA;
      *(uint2*)(vtd + r * 64 + cB * 8 + (c & 1) * 4) = vB;
    }
  };

  stage(Ks[0], Vt[0], 0);
  int cur = 0;
  for (int t = 0; t < Nc / 64; ++t) {
    __syncthreads();  // drains vmcnt+lgkm: tile t visible; prev reads closed
    if (t < Nc / 64 - 1) stage(Ks[cur ^ 1], Vt[cur ^ 1], t + 1);

    const uint16_t* ksp = &Ks[cur][0];
    const uint16_t* vtp = &Vt[cur][0];

    // QK^T: St[c] reg r = S'[kv = c*32 + (r&3) + 8*(r>>2) + 4*hi][q=l31] - mrow
    f32x16 St[2];
#pragma unroll
    for (int r = 0; r < 16; ++r) { St[0][r] = -mrow; St[1][r] = -mrow; }
    __builtin_amdgcn_s_setprio(1);
#pragma unroll
    for (int c = 0; c < 2; ++c)
#pragma unroll
      for (int ks = 0; ks < 4; ++ks) {
        bf16x8 kf = *(const bf16x8*)(&ksp[(c * 32 + l31) * 64 +
                                          (((ks * 2 + hi) ^ sw) * 8)]);
        St[c] = MFMA32(kf, qf[ks], St[c]);
      }
    __builtin_amdgcn_s_setprio(0);

    // in-lane max over 32, then combine with partner lane (^32)
    f32x16 mm;
#pragma unroll
    for (int r = 0; r < 16; ++r) mm[r] = fmaxf(St[0][r], St[1][r]);
    float m8[8];
#pragma unroll
    for (int r = 0; r < 8; ++r) m8[r] = fmaxf(mm[r], mm[r + 8]);
    float pm = fmaxf(fmaxf(fmaxf(m8[0], m8[1]), fmaxf(m8[2], m8[3])),
                     fmaxf(fmaxf(m8[4], m8[5]), fmaxf(m8[6], m8[7])));
    pm = fmaxf(pm, __shfl_xor(pm, 32));

    // defer-rescale: only when max grew by > 11.5 (log2 units)
    if (__any(pm > 11.5f)) {
      const float dd = fmaxf(pm, 0.f);
      mrow += dd;
      const float corr = fexp2(-dd);
      lrow *= corr;
      O16[0] *= corr;
      O16[1] *= corr;
      St[0] -= dd;
      St[1] -= dd;
    }

#pragma unroll
    for (int r = 0; r < 16; ++r) {
      St[0][r] = fexp2(St[0][r]);
      St[1][r] = fexp2(St[1][r]);
    }

    // P B-fragments: pure register renaming. Window m covers kv [16m, 16m+16);
    // k-slot hi*8+j maps to kv = 16m + 4hi + (j&3) + 8*(j>>2) — exactly the
    // St regs below (c = m>>1, rr = (m&1)*2).
    bf16x8 pa[4];
#pragma unroll
    for (int m = 0; m < 4; ++m) {
      const int c = m >> 1, rr = (m & 1) * 2;
#pragma unroll
      for (int j = 0; j < 4; ++j) {
        pa[m][j] = (__bf16)St[c][rr * 4 + j];
        pa[m][j + 4] = (__bf16)St[c][rr * 4 + 4 + j];
      }
    }

    // denominator: ones-MFMA sums all 64 kv (any permutation), in-lane col=q
    f32x16 ls = {};
    __builtin_amdgcn_s_setprio(1);
#pragma unroll
    for (int m = 0; m < 4; ++m) ls = MFMA32(onef, pa[m], ls);

    // PV: O16[df] += mfma32(V-frag, pa[m]); V-frag = ONE b128 read from the
    // interleaved layout (chunk (2m+hi)^sw, k-order = byte order).
#pragma unroll
    for (int df = 0; df < 2; ++df) {
      const int drow = df * 32 + l31;
#pragma unroll
      for (int m = 0; m < 4; ++m) {
        bf16x8 vf = *(const bf16x8*)(&vtp[drow * 64 + (((2 * m + hi) ^ sw) * 8)]);
        O16[df] = MFMA32(vf, pa[m], O16[df]);
      }
    }
    __builtin_amdgcn_s_setprio(0);
    lrow += ls[0];
    cur ^= 1;
  }

  // epilogue: per-lane normalize (q = l31), packed 8B stores.
  // O16[df] reg r -> d = df*32 + (r&3) + 8*(r>>2) + 4*hi.
  const int b = bh >> 4, h = bh & 15;
  const float inv = 1.f / lrow;
  const int n = q0 + wave * 32 + l31;
  uint16_t* orow = Ob + ((size_t)b * Nc + n) * Dc + h * HDc;
#pragma unroll
  for (int df = 0; df < 2; ++df)
#pragma unroll
    for (int r2 = 0; r2 < 4; ++r2) {
      uint2 pv;
      pv.x = (uint32_t)f2bf(O16[df][r2 * 4 + 0] * inv) |
             ((uint32_t)f2bf(O16[df][r2 * 4 + 1] * inv) << 16);
      pv.y = (uint32_t)f2bf(O16[df][r2 * 4 + 2] * inv) |
             ((uint32_t)f2bf(O16[df][r2 * 4 + 3] * inv) << 16);
      *(uint2*)(orow + df * 32 + r2 * 8 + hi * 4) = pv;
    }
}

extern "C" void kernel_launch(void* const* d_in, const int* in_sizes, int n_in,
                              void* d_out, int out_size, void* d_ws, size_t ws_size,
                              hipStream_t stream) {
  const float* x = (const float*)d_in[0];      // [B,N,D] f32
  const float* rot = (const float*)d_in[1];    // [B,N,D,2] f32
  const float* Wqkv = (const float*)d_in[2];   // [3D,D] f32
  const float* Wout = (const float*)d_in[3];   // [D,D] f32
  const float* bout = (const float*)d_in[4];   // [D] f32
  float* out = (float*)d_out;                  // [B,N,D] f32

  uint16_t* ws = (uint16_t*)d_ws;
  const size_t XSZ = (size_t)Bc * Nc * Dc;        // 16,777,216 elems
  const size_t W1SZ = (size_t)3 * Dc * Dc;        //  3,145,728
  const size_t W2SZ = (size_t)Dc * Dc;            //  1,048,576
  uint16_t* xb = ws;               // bf16 x; ALIASED with At (safe: xb's last
  uint16_t* At = ws;               // read is gemm1; At first written by attn)
  uint16_t* Qb = ws + XSZ;
  uint16_t* Kb = ws + 2 * XSZ;
  uint16_t* Vg = ws + 3 * XSZ;     // transposed [B,H,HD,N]
  uint16_t* Wqb = ws + 4 * XSZ;
  uint16_t* Wob = ws + 4 * XSZ + W1SZ;
  // total: 4*XSZ + W1SZ + W2SZ = 71,303,168 elems = 142.6 MB

  dim3 blk(256);
  cvt_f32_bf16<<<dim3((XSZ / 8 + 255) / 256), blk, 0, stream>>>(x, xb, (int)XSZ);
  cvt_f32_bf16<<<dim3((W1SZ / 8 + 255) / 256), blk, 0, stream>>>(Wqkv, Wqb, (int)W1SZ);
  cvt_f32_bf16<<<dim3((W2SZ / 8 + 255) / 256), blk, 0, stream>>>(Wout, Wob, (int)W2SZ);

  gemm_bt<0><<<dim3((3 * Dc) / 128, (Bc * Nc) / 128), blk, 0, stream>>>(
      xb, Wqb, Dc, rot, Qb, Kb, Vg, nullptr, nullptr);
  attn_fa<<<dim3(Nc / 128, Bc * Hc), blk, 0, stream>>>(Qb, Kb, Vg, At);
  gemm_bt<1><<<dim3(Dc / 128, (Bc * Nc) / 128), blk, 0, stream>>>(
      At, Wob, Dc, nullptr, nullptr, nullptr, nullptr, bout, out);
}

// Round 12
// 580.771 us; speedup vs baseline: 2.0937x; 1.0320x over previous
//
#include <hip/hip_runtime.h>
#include <hip/hip_bf16.h>
#include <stdint.h>
#include <stddef.h>

typedef __attribute__((ext_vector_type(8))) __bf16 bf16x8;
typedef __attribute__((ext_vector_type(4))) float f32x4;
typedef __attribute__((ext_vector_type(16))) float f32x16;

#define MFMA16(a, b, c) __builtin_amdgcn_mfma_f32_16x16x32_bf16((a), (b), (c), 0, 0, 0)
#define MFMA32(a, b, c) __builtin_amdgcn_mfma_f32_32x32x16_bf16((a), (b), (c), 0, 0, 0)
#define MAX3(a, b, c) fmaxf(fmaxf((a), (b)), (c))

static constexpr int Bc = 4, Nc = 4096, Dc = 1024, Hc = 16, HDc = 64;

__device__ __forceinline__ uint16_t f2bf(float f) {
  __bf16 h = (__bf16)f;
  return __builtin_bit_cast(uint16_t, h);
}

// raw v_exp_f32 (no libm edge-case code; inputs here are finite, bounded)
__device__ __forceinline__ float fexp2(float x) {
#if __has_builtin(__builtin_amdgcn_exp2f)
  return __builtin_amdgcn_exp2f(x);
#else
  return __builtin_exp2f(x);
#endif
}

// async global->LDS, 16B per lane. LDS dest must be wave-uniform base + lane*16.
__device__ __forceinline__ void gload16(const void* g, void* l) {
  __builtin_amdgcn_global_load_lds(
      (__attribute__((address_space(1))) void*)(g),
      (__attribute__((address_space(3))) void*)(l), 16, 0, 0);
}

// ---------------------------------------------------------------------------
// f32 -> bf16 convert (vectorized, 8 elems/thread). n must be a multiple of 8.
// ---------------------------------------------------------------------------
__global__ __launch_bounds__(256) void cvt_f32_bf16(
    const float* __restrict__ src, uint16_t* __restrict__ dst, int n) {
  const int i = (blockIdx.x * 256 + threadIdx.x) * 8;
  if (i >= n) return;
  const float4 a = *(const float4*)(src + i);
  const float4 b = *(const float4*)(src + i + 4);
  union { uint16_t u[8]; uint4 v; } o;
  o.u[0] = f2bf(a.x); o.u[1] = f2bf(a.y); o.u[2] = f2bf(a.z); o.u[3] = f2bf(a.w);
  o.u[4] = f2bf(b.x); o.u[5] = f2bf(b.y); o.u[6] = f2bf(b.z); o.u[7] = f2bf(b.w);
  *(uint4*)(dst + i) = o.v;
}

// ---------------------------------------------------------------------------
// BT-GEMM: C[m, e] = sum_k A[m, k] * Bw[e, k].  128x128 tile, BK=64, 4 waves.
// EPI=0: QKV projection epilogue -> RoPE (f32 rot) -> Q/K [B,H,N,HD] bf16,
//        Q pre-scaled by 0.125*log2(e) (exp2-domain softmax),
//        V transposed [B,H,HD,N] bf16
// EPI=1: bias add (f32) -> Out [M, 1024] f32
// ---------------------------------------------------------------------------
template <int EPI>
__global__ __launch_bounds__(256, 2) void gemm_bt(
    const uint16_t* __restrict__ A, const uint16_t* __restrict__ Bw, int K,
    const float* __restrict__ rot, uint16_t* __restrict__ Qb,
    uint16_t* __restrict__ Kb, uint16_t* __restrict__ Vg,
    const float* __restrict__ bias, float* __restrict__ Out) {
  __shared__ __align__(16) uint16_t As[128 * 64];
  __shared__ __align__(16) uint16_t Bs[128 * 64];
  const int tid = threadIdx.x;
  const int lane = tid & 63, wave = tid >> 6;
  const int l15 = lane & 15, g = lane >> 4;
  const int wr = wave >> 1, wc = wave & 1;
  const int m0 = blockIdx.y * 128;
  const int n0 = blockIdx.x * 128;

  f32x4 acc[4][4];
  const f32x4 fz = {0.f, 0.f, 0.f, 0.f};
#pragma unroll
  for (int i = 0; i < 4; ++i)
#pragma unroll
    for (int j = 0; j < 4; ++j) acc[i][j] = fz;

  for (int kt = 0; kt < K; kt += 64) {
    __syncthreads();  // previous iter's LDS reads done before overwrite
#pragma unroll
    for (int i = 0; i < 4; ++i) {
      const int chunk = tid + i * 256;  // 0..1023 : 128 rows x 8 chunks(16B)
      const int r = chunk >> 3, c = chunk & 7;
      const int cs = c ^ (r & 7);  // pre-swizzled source (linear LDS dest)
      gload16(A + (size_t)(m0 + r) * K + kt + cs * 8, &As[chunk * 8]);
      gload16(Bw + (size_t)(n0 + r) * K + kt + cs * 8, &Bs[chunk * 8]);
    }
    __syncthreads();  // implies vmcnt(0): staged data visible

    bf16x8 af[4][2], bfr[4][2];
#pragma unroll
    for (int mi = 0; mi < 4; ++mi)
#pragma unroll
      for (int kk = 0; kk < 2; ++kk) {
        const int r = wr * 64 + mi * 16 + l15;
        const int ca = (kk * 4 + g) ^ (r & 7);
        af[mi][kk] = *(const bf16x8*)((const char*)As + r * 128 + ca * 16);
        const int r2 = wc * 64 + mi * 16 + l15;
        const int cb = (kk * 4 + g) ^ (r2 & 7);
        bfr[mi][kk] = *(const bf16x8*)((const char*)Bs + r2 * 128 + cb * 16);
      }
#pragma unroll
    for (int mi = 0; mi < 4; ++mi)
#pragma unroll
      for (int nj = 0; nj < 4; ++nj)
#pragma unroll
        for (int kk = 0; kk < 2; ++kk)
          acc[mi][nj] = MFMA16(af[mi][kk], bfr[nj][kk], acc[mi][nj]);
  }

  if (EPI == 0) {
    // C rows m -> (b, n); cols e -> (part, h, hd). RoPE pair is lane^1.
    const int b = m0 >> 12;  // 4096 rows per batch, 128 | 4096 -> uniform
#pragma unroll
    for (int nj = 0; nj < 4; ++nj) {
      const int e = n0 + wc * 64 + nj * 16 + l15;
      const int part = e >> 10;           // wave-uniform (16-col tile)
      const int d = e & 1023;
      const int h = d >> 6, hd = d & 63;
      // exp2-domain: fold 0.125*log2(e) into Q
      const float sc = (part == 0) ? 0.18033688011112042f : 1.0f;
#pragma unroll
      for (int mi = 0; mi < 4; ++mi) {
        if (part == 2) {
          // V transposed: [B, H, HD, N]; pack 4 consecutive n into 8B store
          const int nb = (m0 & 4095) + wr * 64 + mi * 16 + g * 4;
          uint2 pv;
          pv.x = (uint32_t)f2bf(acc[mi][nj][0]) |
                 ((uint32_t)f2bf(acc[mi][nj][1]) << 16);
          pv.y = (uint32_t)f2bf(acc[mi][nj][2]) |
                 ((uint32_t)f2bf(acc[mi][nj][3]) << 16);
          *(uint2*)(Vg + ((size_t)(b * Hc + h) * HDc + hd) * Nc + nb) = pv;
        } else {
          uint16_t* dst = (part == 0) ? Qb : Kb;
          const size_t base = ((size_t)(b * Hc + h) * Nc) * HDc + hd;
#pragma unroll
          for (int rg = 0; rg < 4; ++rg) {
            const int m = m0 + wr * 64 + mi * 16 + g * 4 + rg;
            const int n = m & (Nc - 1);
            const float val = acc[mi][nj][rg];
            const float partner = __shfl_xor(val, 1);
            const float x2 = (e & 1) ? partner : -partner;
            const float2 cs =
                *(const float2*)(rot + ((size_t)(b * Nc + n) * Dc + d) * 2);
            dst[base + (size_t)n * HDc] = f2bf((val * cs.x + x2 * cs.y) * sc);
          }
        }
      }
    }
  } else {
#pragma unroll
    for (int nj = 0; nj < 4; ++nj) {
      const int e = n0 + wc * 64 + nj * 16 + l15;
      const float bia = bias[e];
#pragma unroll
      for (int mi = 0; mi < 4; ++mi)
#pragma unroll
        for (int rg = 0; rg < 4; ++rg) {
          const int m = m0 + wr * 64 + mi * 16 + g * 4 + rg;
          Out[(size_t)m * Dc + e] = acc[mi][nj][rg] + bia;
        }
    }
  }
}

// ---------------------------------------------------------------------------
// Flash attention, 32x32x16 MFMA, in-register P, interleaved V LDS — exact
// r10 structure (runtime-cur double buffer, launch_bounds(256,3), one barrier
// per tile; r11's unrolled-dbuf + bounds-4 variant raced and is reverted).
// New vs r10: XCD-clustered flat grid (all 32 q-blocks of one bh on one XCD
// -> K/V L2-resident) and max3-shaped reduction tree.
// ---------------------------------------------------------------------------
__global__ __launch_bounds__(256, 3) void attn_fa(
    const uint16_t* __restrict__ Qb, const uint16_t* __restrict__ Kb,
    const uint16_t* __restrict__ Vg, uint16_t* __restrict__ Ob) {
  __shared__ __align__(16) uint16_t Ks[2][64 * 64];  // [kv][d], chunk-swizzled
  __shared__ __align__(16) uint16_t Vt[2][64 * 64];  // [d][kv-interleaved]
  const int tid = threadIdx.x;
  const int lane = tid & 63, wave = tid >> 6;
  const int l31 = lane & 31, hi = lane >> 5;
  const int sw = l31 & 7;  // swizzle index (row&7 for all row sets used)
  // XCD-clustered bijective remap: id%8 = XCD slot; all 32 q-blocks of a bh
  // land on one XCD -> that L2 only holds its own 8 bh's K/V (~6MB).
  const int id = blockIdx.x;
  const int kk2 = id >> 3;
  const int bh = (id & 7) + 8 * (kk2 >> 5);
  const int q0 = (kk2 & 31) * 128;
  const size_t bhN = (size_t)bh * Nc;
  const size_t bhHD = (size_t)bh * HDc;

  // Q B-fragments (col = q = l31, k(d) = ks*16 + hi*8 + j), register-resident
  bf16x8 qf[4];
#pragma unroll
  for (int ks = 0; ks < 4; ++ks)
    qf[ks] = *(const bf16x8*)(Qb + (bhN + q0 + wave * 32 + l31) * HDc +
                              ks * 16 + hi * 8);

  // all-ones A-fragment for the denominator MFMA
  bf16x8 onef;
#pragma unroll
  for (int j = 0; j < 8; ++j) onef[j] = (__bf16)1.0f;

  f32x16 O16[2] = {{}, {}};
  float mrow = 0.f, lrow = 0.f;  // defer-max: start at 0, rescale on >11.5

  // stage K (gload_lds, linear dest / pre-swz source) and V (reg-staged,
  // interleaved dest) for tile t.
  auto stage = [&](uint16_t* ksd, uint16_t* vtd, int t) {
    const int kv0 = t * 64;
#pragma unroll
    for (int i = 0; i < 2; ++i) {
      const int ch = tid + i * 256;  // 0..511 : 64 rows x 8 chunks(16B)
      const int r = ch >> 3, c = ch & 7;
      const int cs = c ^ (r & 7);
      gload16(Kb + (bhN + kv0 + r) * HDc + cs * 8, ksd + ch * 8);
      // V: global chunk c (kv c*8..c*8+7) -> LDS chunks (2*(c>>1)+{0,1})^(r&7),
      // 8B halves at byte offset 8*(c&1).
      const uint4 gv = *(const uint4*)(Vg + (bhHD + r) * Nc + kv0 + c * 8);
      const int cA = (2 * (c >> 1)) ^ (r & 7);
      const int cB = (2 * (c >> 1) + 1) ^ (r & 7);
      uint2 vA; vA.x = gv.x; vA.y = gv.y;
      uint2 vB; vB.x = gv.z; vB.y = gv.w;
      *(uint2*)(vtd + r * 64 + cA * 8 + (c & 1) * 4) = vA;
      *(uint2*)(vtd + r * 64 + cB * 8 + (c & 1) * 4) = vB;
    }
  };

  stage(Ks[0], Vt[0], 0);
  int cur = 0;
  for (int t = 0; t < Nc / 64; ++t) {
    __syncthreads();  // drains vmcnt+lgkm: tile t visible; prev reads closed
    if (t < Nc / 64 - 1) stage(Ks[cur ^ 1], Vt[cur ^ 1], t + 1);

    const uint16_t* ksp = &Ks[cur][0];
    const uint16_t* vtp = &Vt[cur][0];

    // QK^T: St[c] reg r = S'[kv = c*32 + (r&3) + 8*(r>>2) + 4*hi][q=l31] - mrow
    f32x16 St[2];
#pragma unroll
    for (int r = 0; r < 16; ++r) { St[0][r] = -mrow; St[1][r] = -mrow; }
    __builtin_amdgcn_s_setprio(1);
#pragma unroll
    for (int c = 0; c < 2; ++c)
#pragma unroll
      for (int ks = 0; ks < 4; ++ks) {
        bf16x8 kf = *(const bf16x8*)(&ksp[(c * 32 + l31) * 64 +
                                          (((ks * 2 + hi) ^ sw) * 8)]);
        St[c] = MFMA32(kf, qf[ks], St[c]);
      }
    __builtin_amdgcn_s_setprio(0);

    // max over 32 in-lane values (max3-shaped tree), then partner lane ^32
    {
      float u0 = MAX3(St[0][0], St[0][1], St[0][2]);
      float u1 = MAX3(St[0][3], St[0][4], St[0][5]);
      float u2 = MAX3(St[0][6], St[0][7], St[0][8]);
      float u3 = MAX3(St[0][9], St[0][10], St[0][11]);
      float u4 = MAX3(St[0][12], St[0][13], St[0][14]);
      float u5 = MAX3(St[0][15], St[1][0], St[1][1]);
      float u6 = MAX3(St[1][2], St[1][3], St[1][4]);
      float u7 = MAX3(St[1][5], St[1][6], St[1][7]);
      float u8 = MAX3(St[1][8], St[1][9], St[1][10]);
      float u9 = MAX3(St[1][11], St[1][12], St[1][13]);
      float ua = fmaxf(St[1][14], St[1][15]);
      float w0 = MAX3(u0, u1, u2);
      float w1 = MAX3(u3, u4, u5);
      float w2 = MAX3(u6, u7, u8);
      float w3 = MAX3(u9, ua, w0);
      float pm = MAX3(w1, w2, w3);
      pm = fmaxf(pm, __shfl_xor(pm, 32));

      // defer-rescale: only when max grew by > 11.5 (log2 units)
      if (__any(pm > 11.5f)) {
        const float dd = fmaxf(pm, 0.f);
        mrow += dd;
        const float corr = fexp2(-dd);
        lrow *= corr;
        O16[0] *= corr;
        O16[1] *= corr;
        St[0] -= dd;
        St[1] -= dd;
      }
    }

#pragma unroll
    for (int r = 0; r < 16; ++r) {
      St[0][r] = fexp2(St[0][r]);
      St[1][r] = fexp2(St[1][r]);
    }

    // P B-fragments: pure register renaming. Window m covers kv [16m, 16m+16);
    // k-slot hi*8+j maps to kv = 16m + 4hi + (j&3) + 8*(j>>2) — exactly the
    // St regs below (c = m>>1, rr = (m&1)*2).
    bf16x8 pa[4];
#pragma unroll
    for (int m = 0; m < 4; ++m) {
      const int c = m >> 1, rr = (m & 1) * 2;
#pragma unroll
      for (int j = 0; j < 4; ++j) {
        pa[m][j] = (__bf16)St[c][rr * 4 + j];
        pa[m][j + 4] = (__bf16)St[c][rr * 4 + 4 + j];
      }
    }

    // denominator: ones-MFMA sums all 64 kv (any permutation), in-lane col=q
    f32x16 ls = {};
    __builtin_amdgcn_s_setprio(1);
#pragma unroll
    for (int m = 0; m < 4; ++m) ls = MFMA32(onef, pa[m], ls);

    // PV: O16[df] += mfma32(V-frag, pa[m]); V-frag = ONE b128 read from the
    // interleaved layout (chunk (2m+hi)^sw, k-order = byte order).
#pragma unroll
    for (int df = 0; df < 2; ++df) {
      const int drow = df * 32 + l31;
#pragma unroll
      for (int m = 0; m < 4; ++m) {
        bf16x8 vf = *(const bf16x8*)(&vtp[drow * 64 + (((2 * m + hi) ^ sw) * 8)]);
        O16[df] = MFMA32(vf, pa[m], O16[df]);
      }
    }
    __builtin_amdgcn_s_setprio(0);
    lrow += ls[0];
    cur ^= 1;
  }

  // epilogue: per-lane normalize (q = l31), packed 8B stores.
  // O16[df] reg r -> d = df*32 + (r&3) + 8*(r>>2) + 4*hi.
  const int b = bh >> 4, h = bh & 15;
  const float inv = 1.f / lrow;
  const int n = q0 + wave * 32 + l31;
  uint16_t* orow = Ob + ((size_t)b * Nc + n) * Dc + h * HDc;
#pragma unroll
  for (int df = 0; df < 2; ++df)
#pragma unroll
    for (int r2 = 0; r2 < 4; ++r2) {
      uint2 pv;
      pv.x = (uint32_t)f2bf(O16[df][r2 * 4 + 0] * inv) |
             ((uint32_t)f2bf(O16[df][r2 * 4 + 1] * inv) << 16);
      pv.y = (uint32_t)f2bf(O16[df][r2 * 4 + 2] * inv) |
             ((uint32_t)f2bf(O16[df][r2 * 4 + 3] * inv) << 16);
      *(uint2*)(orow + df * 32 + r2 * 8 + hi * 4) = pv;
    }
}

extern "C" void kernel_launch(void* const* d_in, const int* in_sizes, int n_in,
                              void* d_out, int out_size, void* d_ws, size_t ws_size,
                              hipStream_t stream) {
  const float* x = (const float*)d_in[0];      // [B,N,D] f32
  const float* rot = (const float*)d_in[1];    // [B,N,D,2] f32
  const float* Wqkv = (const float*)d_in[2];   // [3D,D] f32
  const float* Wout = (const float*)d_in[3];   // [D,D] f32
  const float* bout = (const float*)d_in[4];   // [D] f32
  float* out = (float*)d_out;                  // [B,N,D] f32

  uint16_t* ws = (uint16_t*)d_ws;
  const size_t XSZ = (size_t)Bc * Nc * Dc;        // 16,777,216 elems
  const size_t W1SZ = (size_t)3 * Dc * Dc;        //  3,145,728
  const size_t W2SZ = (size_t)Dc * Dc;            //  1,048,576
  uint16_t* xb = ws;               // bf16 x; ALIASED with At (safe: xb's last
  uint16_t* At = ws;               // read is gemm1; At first written by attn)
  uint16_t* Qb = ws + XSZ;
  uint16_t* Kb = ws + 2 * XSZ;
  uint16_t* Vg = ws + 3 * XSZ;     // transposed [B,H,HD,N]
  uint16_t* Wqb = ws + 4 * XSZ;
  uint16_t* Wob = ws + 4 * XSZ + W1SZ;
  // total: 4*XSZ + W1SZ + W2SZ = 71,303,168 elems = 142.6 MB

  dim3 blk(256);
  cvt_f32_bf16<<<dim3((XSZ / 8 + 255) / 256), blk, 0, stream>>>(x, xb, (int)XSZ);
  cvt_f32_bf16<<<dim3((W1SZ / 8 + 255) / 256), blk, 0, stream>>>(Wqkv, Wqb, (int)W1SZ);
  cvt_f32_bf16<<<dim3((W2SZ / 8 + 255) / 256), blk, 0, stream>>>(Wout, Wob, (int)W2SZ);

  gemm_bt<0><<<dim3((3 * Dc) / 128, (Bc * Nc) / 128), blk, 0, stream>>>(
      xb, Wqb, Dc, rot, Qb, Kb, Vg, nullptr, nullptr);
  attn_fa<<<dim3((Nc / 128) * (Bc * Hc)), blk, 0, stream>>>(Qb, Kb, Vg, At);
  gemm_bt<1><<<dim3(Dc / 128, (Bc * Nc) / 128), blk, 0, stream>>>(
      At, Wob, Dc, nullptr, nullptr, nullptr, nullptr, bout, out);
}